// Round 15
// baseline (868.861 us; speedup 1.0000x reference)
//
#include <hip/hip_runtime.h>
#include <hip/hip_bf16.h>
#include <cfloat>

constexpr int BATCH = 8, NPTS = 2048, KNN = 20;
constexpr int NROWS = BATCH * NPTS;
constexpr float EPSV = 1e-5f;
constexpr int SB = 256;                          // statsb blocks per batch
constexpr int PR = 64;                           // reduced partials
constexpr int RBB = NPTS / 16;                   // row-blocks per batch (128)
constexpr int KCAP = 64;                         // knn per-row candidate cap
constexpr int QCAP = 512;                        // stage-1 topk queue cap

using u16 = unsigned short;
using u64 = unsigned long long;
typedef __attribute__((ext_vector_type(8))) short short8;
typedef __attribute__((ext_vector_type(4))) float f32x4;

// ---------------------------------------------------------------- diag / fill
__global__ void diag_kernel(float* out, float v) {
    if (threadIdx.x < 8) out[threadIdx.x] = v;
}

__global__ __launch_bounds__(256) void fill_zero_kernel(float* __restrict__ p, int n) {
    int i = blockIdx.x * 256 + threadIdx.x;
    if (i < n) p[i] = 0.f;
}

// ---------------------------------------------------------------- sqnorm over all rows
template<int C>
__global__ __launch_bounds__(256) void sqnorm_kernel(const float* __restrict__ X,
                                                     float* __restrict__ sq) {
    int r = blockIdx.x * 256 + threadIdx.x;
    const float* x = X + (size_t)r * C;
    float s = 0.f;
#pragma unroll
    for (int c = 0; c < C; ++c) { float v = x[c]; s = fmaf(v, v, s); }
    sq[r] = s;
}

// ---------------------------------------------------------------- split X -> hi/lo bf16 in PACKED MFMA-fragment layout
template<int C>
__global__ __launch_bounds__(256) void split_pack_kernel(const float* __restrict__ X,
                                                         u16* __restrict__ XPH,
                                                         u16* __restrict__ XPL) {
    constexpr int KB = C / 32;
    int e = blockIdx.x * 256 + threadIdx.x;     // one short8 fragment per thread
    int lane = e & 63;
    int rest = e >> 6;
    int kb = rest % KB;
    int Rb = rest / KB;
    int row = Rb * 16 + (lane & 15);
    int col = kb * 32 + (lane >> 4) * 8;
    const float* src = &X[(size_t)row * C + col];
    u16 h[8], l[8];
#pragma unroll
    for (int q = 0; q < 8; ++q) {
        float v = src[q];
        __hip_bfloat16 hb = __float2bfloat16(v);
        float hf = __bfloat162float(hb);
        __hip_bfloat16 lb = __float2bfloat16(v - hf);
        h[q] = *(u16*)&hb; l[q] = *(u16*)&lb;
    }
    u16* dh = &XPH[(size_t)e * 8];
    u16* dl = &XPL[(size_t)e * 8];
#pragma unroll
    for (int q = 0; q < 8; ++q) { dh[q] = h[q]; dl[q] = l[q]; }
}

// ---------------------------------------------------------------- split W -> packed hi/lo (n<O: W1; n>=O: W2-W1)
template<int C, int O>
__global__ __launch_bounds__(256) void wsplit_pack_kernel(const float* __restrict__ W,
                                                          u16* __restrict__ WPH,
                                                          u16* __restrict__ WPL) {
    constexpr int KB = C / 32;
    constexpr int NFRAG = (2 * O / 16) * KB * 64;
    int e = blockIdx.x * 256 + threadIdx.x;
    if (e >= NFRAG) return;
    int lane = e & 63;
    int rest = e >> 6;
    int kb = rest % KB;
    int Nb = rest / KB;
    int n = Nb * 16 + (lane & 15);
    int col = kb * 32 + (lane >> 4) * 8;
    u16 h[8], l[8];
#pragma unroll
    for (int q = 0; q < 8; ++q) {
        int c = col + q;
        float wv = (n < O) ? W[(size_t)n * (2 * C) + c]
                           : W[(size_t)(n - O) * (2 * C) + C + c] - W[(size_t)(n - O) * (2 * C) + c];
        __hip_bfloat16 hb = __float2bfloat16(wv);
        float hf = __bfloat162float(hb);
        __hip_bfloat16 lb = __float2bfloat16(wv - hf);
        h[q] = *(u16*)&hb; l[q] = *(u16*)&lb;
    }
    u16* dh = &WPH[(size_t)e * 8];
    u16* dl = &WPL[(size_t)e * 8];
#pragma unroll
    for (int q = 0; q < 8; ++q) { dh[q] = h[q]; dl[q] = l[q]; }
}

// ---------------------------------------------------------------- wave-64 bitonic sorts
__device__ __forceinline__ float bitonic64_desc_f32(float key, int lane) {
#pragma unroll
    for (int k = 2; k <= 64; k <<= 1) {
#pragma unroll
        for (int j = k >> 1; j > 0; j >>= 1) {
            float p = __shfl_xor(key, j);
            bool keepMax = (((lane & j) == 0) == ((lane & k) == 0));
            key = ((key > p) == keepMax) ? key : p;
        }
    }
    return key;
}

__device__ __forceinline__ u64 bitonic64_desc_u64(u64 key, int lane) {
#pragma unroll
    for (int k = 2; k <= 64; k <<= 1) {
#pragma unroll
        for (int j = k >> 1; j > 0; j >>= 1) {
            u64 p = __shfl_xor(key, j);
            bool keepMax = (((lane & j) == 0) == ((lane & k) == 0));
            key = ((key > p) == keepMax) ? key : p;
        }
    }
    return key;
}

// ---------------------------------------------------------------- f32 dist GEMM (stage 1, exact; z = batch chunk)
template<int C>
__global__ __launch_bounds__(256) void dist_gemm_kernel(const float* __restrict__ X,
                                                        float* __restrict__ D, int b0) {
    constexpr int KC = (C < 32) ? C : 32;
    __shared__ __align__(16) float As[KC][68];
    __shared__ __align__(16) float Bs[KC][68];
    int b = b0 + blockIdx.z;
    int i0 = blockIdx.y * 64, j0 = blockIdx.x * 64;
    const float* Xb = X + (size_t)b * NPTS * C;
    int tx = threadIdx.x & 15, ty = threadIdx.x >> 4;
    float acc[4][4] = {};
    for (int c0 = 0; c0 < C; c0 += KC) {
        for (int t = threadIdx.x; t < 64 * KC; t += 256) {
            int i = t / KC, c = t % KC;
            As[c][i] = Xb[(size_t)(i0 + i) * C + c0 + c];
            Bs[c][i] = Xb[(size_t)(j0 + i) * C + c0 + c];
        }
        __syncthreads();
#pragma unroll
        for (int c = 0; c < KC; ++c) {
            const float4 av = *(const float4*)&As[c][ty * 4];
            const float4 bv = *(const float4*)&Bs[c][tx * 4];
            float ar[4] = {av.x, av.y, av.z, av.w};
            float br[4] = {bv.x, bv.y, bv.z, bv.w};
#pragma unroll
            for (int r = 0; r < 4; ++r)
#pragma unroll
                for (int q = 0; q < 4; ++q) acc[r][q] = fmaf(ar[r], br[q], acc[r][q]);
        }
        __syncthreads();
    }
    float* Dz = D + (size_t)blockIdx.z * NPTS * NPTS;
#pragma unroll
    for (int r = 0; r < 4; ++r) {
        float4 o4 = make_float4(acc[r][0], acc[r][1], acc[r][2], acc[r][3]);
        *(float4*)&Dz[(size_t)(i0 + ty * 4 + r) * NPTS + j0 + tx * 4] = o4;
    }
}

// ---------------------------------------------------------------- stage-1 top-k from materialized D (exact)
__global__ __launch_bounds__(256) void topk_kernel(const float* __restrict__ D,
                                                   const float* __restrict__ sq,
                                                   u16* __restrict__ idx_out, int b0) {
    __shared__ u64 qkey[4][QCAP];
    __shared__ int qn[4];
    int b = b0 + blockIdx.z;
    int w = threadIdx.x >> 6, lane = threadIdx.x & 63;
    int i = blockIdx.x * 4 + w;
    const float* Drow = D + ((size_t)blockIdx.z * NPTS + i) * NPTS;
    const float* sqb = sq + b * NPTS;
    float sqi = sqb[i];
    if (lane == 0) qn[w] = 0;

    float vals[32];
    float mx = -FLT_MAX;
#pragma unroll
    for (int t = 0; t < 8; ++t) {
        int j = t * 256 + lane * 4;
        float4 v4 = *(const float4*)&Drow[j];
        float4 s4 = *(const float4*)&sqb[j];
        float a0 = (2.f * v4.x - sqi - s4.x) + 0.f;
        float a1 = (2.f * v4.y - sqi - s4.y) + 0.f;
        float a2 = (2.f * v4.z - sqi - s4.z) + 0.f;
        float a3 = (2.f * v4.w - sqi - s4.w) + 0.f;
        vals[t * 4 + 0] = a0; vals[t * 4 + 1] = a1;
        vals[t * 4 + 2] = a2; vals[t * 4 + 3] = a3;
        mx = fmaxf(mx, fmaxf(fmaxf(a0, a1), fmaxf(a2, a3)));
    }

    float sm = bitonic64_desc_f32(mx, lane);
    float T0 = __shfl(sm, 19);

#pragma unroll
    for (int t = 0; t < 32; ++t) {
        float v = vals[t];
        if (v >= T0) {
            unsigned j = (unsigned)((t >> 2) * 256 + lane * 4 + (t & 3));
            unsigned bu = __float_as_uint(v);
            unsigned u = (bu & 0x80000000u) ? ~bu : (bu | 0x80000000u);
            u64 key = ((u64)u << 32) | (u64)(0xFFFFFFFFu - j);
            int slot = atomicAdd(&qn[w], 1);
            if (slot < QCAP) qkey[w][slot] = key;
        }
    }
    int C = qn[w];
    if (C > QCAP) C = QCAP;

    u64 key = (lane < C) ? qkey[w][lane] : 0ull;
    key = bitonic64_desc_u64(key, lane);
    int base = 64;
    while (base < C) {
        if (lane >= 20) {
            int src = base + (lane - 20);
            key = (src < C) ? qkey[w][src] : 0ull;
        }
        key = bitonic64_desc_u64(key, lane);
        base += 44;
    }
    if (lane < 20) {
        unsigned j = 0xFFFFFFFFu - (unsigned)(key & 0xFFFFFFFFull);
        idx_out[(size_t)(b * NPTS + i) * KNN + lane] = (u16)j;
    }
}

// ---------------------------------------------------------------- fused kNN (stages 2..4): MFMA dist (not materialized) + exact top-20
template<int C>
__global__ __launch_bounds__(256) void knn_kernel(const u16* __restrict__ XPH,
                                                  const u16* __restrict__ XPL,
                                                  const float* __restrict__ SQ,
                                                  u64* __restrict__ CAND) {
    constexpr int KB = C / 32;
    __shared__ float cmax[64][65];
    __shared__ u64 cand[64][KCAP];
    __shared__ float Ts[64];
    __shared__ int cnt[64];
    int b = blockIdx.z;
    int chunk = blockIdx.x;                      // 0..1
    int i0 = blockIdx.y * 64;
    int w = threadIdx.x >> 6, lane = threadIdx.x & 63;
    int l15 = lane & 15, g = lane >> 4;
    size_t base = (size_t)b * RBB * KB * 512;
    const float* sqb = SQ + b * NPTS;

    int Rba = i0 / 16 + w;
    short8 ahi[KB], alo[KB];
#pragma unroll
    for (int kb = 0; kb < KB; ++kb) {
        size_t ia = base + ((size_t)(Rba * KB + kb) * 64 + lane) * 8;
        ahi[kb] = *(const short8*)&XPH[ia];
        alo[kb] = *(const short8*)&XPL[ia];
    }
    int rbase = i0 + w * 16 + g * 4;
    float sqr[4];
#pragma unroll
    for (int r = 0; r < 4; ++r) sqr[r] = sqb[rbase + r];

    // ---- pass A: per-row class maxima (64 classes = (l15,nt))
    float rm[4][4];
#pragma unroll
    for (int r = 0; r < 4; ++r)
#pragma unroll
        for (int nt = 0; nt < 4; ++nt) rm[r][nt] = -FLT_MAX;
    for (int jt = 0; jt < 16; ++jt) {
        int j0 = chunk * 1024 + jt * 64;
#pragma unroll
        for (int nt = 0; nt < 4; ++nt) {
            int Rbb = j0 / 16 + nt;
            f32x4 acc = {0.f, 0.f, 0.f, 0.f};
#pragma unroll
            for (int kb = 0; kb < KB; ++kb) {
                size_t ib = base + ((size_t)(Rbb * KB + kb) * 64 + lane) * 8;
                short8 bhi = *(const short8*)&XPH[ib];
                short8 blo = *(const short8*)&XPL[ib];
                acc = __builtin_amdgcn_mfma_f32_16x16x32_bf16(ahi[kb], bhi, acc, 0, 0, 0);
                acc = __builtin_amdgcn_mfma_f32_16x16x32_bf16(ahi[kb], blo, acc, 0, 0, 0);
                acc = __builtin_amdgcn_mfma_f32_16x16x32_bf16(alo[kb], bhi, acc, 0, 0, 0);
            }
            int col = j0 + nt * 16 + l15;
            float sqc = sqb[col];
#pragma unroll
            for (int r = 0; r < 4; ++r) {
                float v = (2.f * acc[r] - sqr[r] - sqc) + 0.f;
                rm[r][nt] = fmaxf(rm[r][nt], v);
            }
        }
    }
    int rowloc0 = w * 16 + g * 4;
#pragma unroll
    for (int r = 0; r < 4; ++r)
#pragma unroll
        for (int nt = 0; nt < 4; ++nt)
            cmax[rowloc0 + r][l15 * 4 + nt] = rm[r][nt];
    if (threadIdx.x < 64) cnt[threadIdx.x] = 0;
    __syncthreads();
    for (int rr = 0; rr < 16; ++rr) {
        int row = w * 16 + rr;
        float sv = bitonic64_desc_f32(cmax[row][lane], lane);
        if (lane == 19) Ts[row] = sv;            // 20th largest class max <= true v20
    }
    __syncthreads();

    // ---- pass B: recompute, push candidates >= T
    for (int jt = 0; jt < 16; ++jt) {
        int j0 = chunk * 1024 + jt * 64;
#pragma unroll
        for (int nt = 0; nt < 4; ++nt) {
            int Rbb = j0 / 16 + nt;
            f32x4 acc = {0.f, 0.f, 0.f, 0.f};
#pragma unroll
            for (int kb = 0; kb < KB; ++kb) {
                size_t ib = base + ((size_t)(Rbb * KB + kb) * 64 + lane) * 8;
                short8 bhi = *(const short8*)&XPH[ib];
                short8 blo = *(const short8*)&XPL[ib];
                acc = __builtin_amdgcn_mfma_f32_16x16x32_bf16(ahi[kb], bhi, acc, 0, 0, 0);
                acc = __builtin_amdgcn_mfma_f32_16x16x32_bf16(ahi[kb], blo, acc, 0, 0, 0);
                acc = __builtin_amdgcn_mfma_f32_16x16x32_bf16(alo[kb], bhi, acc, 0, 0, 0);
            }
            int col = j0 + nt * 16 + l15;
            float sqc = sqb[col];
#pragma unroll
            for (int r = 0; r < 4; ++r) {
                float v = (2.f * acc[r] - sqr[r] - sqc) + 0.f;
                int rowloc = rowloc0 + r;
                if (v >= Ts[rowloc]) {
                    unsigned bu = __float_as_uint(v);
                    unsigned u = (bu & 0x80000000u) ? ~bu : (bu | 0x80000000u);
                    u64 key = ((u64)u << 32) | (u64)(0xFFFFFFFFu - (unsigned)col);
                    int slot = atomicAdd(&cnt[rowloc], 1);
                    if (slot < KCAP) cand[rowloc][slot] = key;
                }
            }
        }
    }
    __syncthreads();

    // ---- per-row exact top-20 of candidates
    for (int rr = 0; rr < 16; ++rr) {
        int row = w * 16 + rr;
        int Cn = cnt[row]; if (Cn > KCAP) Cn = KCAP;
        u64 key = (lane < Cn) ? cand[row][lane] : 0ull;
        key = bitonic64_desc_u64(key, lane);
        if (lane < 20)
            CAND[(((size_t)(b * NPTS + i0 + row)) * 2 + chunk) * 20 + lane] = key;
    }
}

// ---------------------------------------------------------------- merge chunk top-20s -> IDX (one wave per row)
__global__ __launch_bounds__(256) void knn_merge_kernel(const u64* __restrict__ CAND,
                                                        u16* __restrict__ idx_out) {
    int b = blockIdx.z;
    int w = threadIdx.x >> 6, lane = threadIdx.x & 63;
    int i = blockIdx.x * 4 + w;
    size_t rb = ((size_t)(b * NPTS + i)) * 40;
    u64 key = (lane < 40) ? CAND[rb + lane] : 0ull;
    key = bitonic64_desc_u64(key, lane);
    if (lane < 20) {
        unsigned j = 0xFFFFFFFFu - (unsigned)(key & 0xFFFFFFFFull);
        idx_out[((size_t)(b * NPTS + i)) * KNN + lane] = (u16)j;
    }
}

// ---------------------------------------------------------------- uvb via MFMA from packed fragments
template<int C, int O>
__global__ __launch_bounds__(256) void uvb_mfma_kernel(const u16* __restrict__ XPH,
                                                       const u16* __restrict__ XPL,
                                                       const u16* __restrict__ WPH,
                                                       const u16* __restrict__ WPL,
                                                       const float* __restrict__ bias,
                                                       float* __restrict__ UVA) {
    constexpr int KB = C / 32;
    int b = blockIdx.z;
    int r0 = blockIdx.y * 64, n0 = blockIdx.x * 64;
    int w = threadIdx.x >> 6, lane = threadIdx.x & 63;
    int l15 = lane & 15, g = lane >> 4;
    size_t base = (size_t)b * RBB * KB * 512;
    int Rba = r0 / 16 + w;
    short8 ahi[KB], alo[KB];
#pragma unroll
    for (int kb = 0; kb < KB; ++kb) {
        size_t ia = base + ((size_t)(Rba * KB + kb) * 64 + lane) * 8;
        ahi[kb] = *(const short8*)&XPH[ia];
        alo[kb] = *(const short8*)&XPL[ia];
    }
    float* UVb = UVA + (size_t)b * NPTS * 2 * O;
#pragma unroll
    for (int nt = 0; nt < 4; ++nt) {
        int Nb = n0 / 16 + nt;
        f32x4 acc = {0.f, 0.f, 0.f, 0.f};
#pragma unroll
        for (int kb = 0; kb < KB; ++kb) {
            size_t ib = ((size_t)(Nb * KB + kb) * 64 + lane) * 8;
            short8 bhi = *(const short8*)&WPH[ib];
            short8 blo = *(const short8*)&WPL[ib];
            acc = __builtin_amdgcn_mfma_f32_16x16x32_bf16(ahi[kb], bhi, acc, 0, 0, 0);
            acc = __builtin_amdgcn_mfma_f32_16x16x32_bf16(ahi[kb], blo, acc, 0, 0, 0);
            acc = __builtin_amdgcn_mfma_f32_16x16x32_bf16(alo[kb], bhi, acc, 0, 0, 0);
        }
        int n = n0 + nt * 16 + l15;
        float badd = (n >= O) ? bias[n - O] : 0.f;
        int rbase = r0 + w * 16 + g * 4;
#pragma unroll
        for (int r = 0; r < 4; ++r)
            UVb[(size_t)(rbase + r) * (2 * O) + n] = acc[r] + badd;
    }
}

// ---------------------------------------------------------------- f32 uvb (stage 1, C=3)
template<int C, int O>
__global__ __launch_bounds__(256) void uvb_gemm_kernel(const float* __restrict__ X,
                                                       const float* __restrict__ W,
                                                       const float* __restrict__ bias,
                                                       float* __restrict__ UVA) {
    constexpr int KC = (C < 32) ? C : 32;
    __shared__ __align__(16) float As[KC][68];
    __shared__ __align__(16) float Bs[KC][68];
    int b = blockIdx.z;
    int r0 = blockIdx.y * 64, n0 = blockIdx.x * 64;
    int tx = threadIdx.x & 15, ty = threadIdx.x >> 4;
    float acc[4][4] = {};
    for (int c0 = 0; c0 < C; c0 += KC) {
        for (int t = threadIdx.x; t < 64 * KC; t += 256) {
            int i = t / KC, c = t % KC;
            As[c][i] = X[(size_t)(b * NPTS + r0 + i) * C + c0 + c];
            int n = n0 + i;
            float wv;
            if (n < O) wv = W[(size_t)n * (2 * C) + c0 + c];
            else {
                int o = n - O;
                wv = W[(size_t)o * (2 * C) + C + c0 + c] - W[(size_t)o * (2 * C) + c0 + c];
            }
            Bs[c][i] = wv;
        }
        __syncthreads();
#pragma unroll
        for (int c = 0; c < KC; ++c) {
            const float4 av = *(const float4*)&As[c][ty * 4];
            const float4 bv = *(const float4*)&Bs[c][tx * 4];
            float ar[4] = {av.x, av.y, av.z, av.w};
            float br[4] = {bv.x, bv.y, bv.z, bv.w};
#pragma unroll
            for (int r = 0; r < 4; ++r)
#pragma unroll
                for (int q = 0; q < 4; ++q) acc[r][q] = fmaf(ar[r], br[q], acc[r][q]);
        }
        __syncthreads();
    }
    float badd[4] = {0.f, 0.f, 0.f, 0.f};
    if (n0 >= O) {
#pragma unroll
        for (int q = 0; q < 4; ++q) badd[q] = bias[n0 - O + tx * 4 + q];
    }
    float* UVb = UVA + (size_t)b * NPTS * 2 * O;
#pragma unroll
    for (int r = 0; r < 4; ++r) {
        float4 o4 = make_float4(acc[r][0] + badd[0], acc[r][1] + badd[1],
                                acc[r][2] + badd[2], acc[r][3] + badd[3]);
        *(float4*)&UVb[(size_t)(r0 + ty * 4 + r) * (2 * O) + n0 + tx * 4] = o4;
    }
}

// ---------------------------------------------------------------- stats: ONE gather pass -> block partials + dense HMAX/HMIN
template<int O>
__global__ __launch_bounds__(256) void statsb_kernel(const float* __restrict__ UVA,
                                                     const u16* __restrict__ idx,
                                                     float* __restrict__ PART,
                                                     float* __restrict__ HMAX,
                                                     float* __restrict__ HMIN) {
    constexpr int TPR = O / 4;
    constexpr int RPAR = 256 / TPR;
    constexpr int RPB = NPTS / SB;
    __shared__ float sh[256 * 8];
    int b = blockIdx.z;
    const float* UVb = UVA + (size_t)b * NPTS * 2 * O;
    int otid = threadIdx.x % TPR;
    int o = otid * 4;
    int rsub = threadIdx.x / TPR;
    int rbase = blockIdx.x * RPB;
    float s0 = 0, s1 = 0, s2 = 0, s3 = 0, q0 = 0, q1 = 0, q2 = 0, q3 = 0;
    for (int r = rbase + rsub; r < rbase + RPB; r += RPAR) {
        const float4 v4 = *(const float4*)&UVb[(size_t)r * (2 * O) + O + o];
        const u16* ix = idx + (size_t)(b * NPTS + r) * KNN;
        float mx0 = -FLT_MAX, mx1 = -FLT_MAX, mx2 = -FLT_MAX, mx3 = -FLT_MAX;
        float mn0 = FLT_MAX, mn1 = FLT_MAX, mn2 = FLT_MAX, mn3 = FLT_MAX;
#pragma unroll
        for (int k = 0; k < KNN; ++k) {
            int j = (int)ix[k] & (NPTS - 1);
            const float4 u4 = *(const float4*)&UVb[(size_t)j * (2 * O) + o];
            float h0 = u4.x + v4.x, h1 = u4.y + v4.y, h2 = u4.z + v4.z, h3 = u4.w + v4.w;
            s0 += h0; q0 = fmaf(h0, h0, q0); mx0 = fmaxf(mx0, h0); mn0 = fminf(mn0, h0);
            s1 += h1; q1 = fmaf(h1, h1, q1); mx1 = fmaxf(mx1, h1); mn1 = fminf(mn1, h1);
            s2 += h2; q2 = fmaf(h2, h2, q2); mx2 = fmaxf(mx2, h2); mn2 = fminf(mn2, h2);
            s3 += h3; q3 = fmaf(h3, h3, q3); mx3 = fmaxf(mx3, h3); mn3 = fminf(mn3, h3);
        }
        size_t R = (size_t)(b * NPTS + r) * O + o;
        *(float4*)&HMAX[R] = make_float4(mx0, mx1, mx2, mx3);
        *(float4*)&HMIN[R] = make_float4(mn0, mn1, mn2, mn3);
    }
    float* my = &sh[threadIdx.x * 8];
    my[0] = s0; my[1] = s1; my[2] = s2; my[3] = s3;
    my[4] = q0; my[5] = q1; my[6] = q2; my[7] = q3;
    __syncthreads();
    if (threadIdx.x < TPR) {
        float a[8];
#pragma unroll
        for (int c = 0; c < 8; ++c) a[c] = sh[threadIdx.x * 8 + c];
        for (int g = 1; g < RPAR; ++g) {
            const float* p = &sh[(g * TPR + threadIdx.x) * 8];
#pragma unroll
            for (int c = 0; c < 8; ++c) a[c] += p[c];
        }
        float* dst = &PART[((size_t)b * SB + blockIdx.x) * (2 * O)];
#pragma unroll
        for (int c = 0; c < 4; ++c) { dst[o + c] = a[c]; dst[O + o + c] = a[4 + c]; }
    }
}

// ---------------------------------------------------------------- PART -> PART2
template<int O>
__global__ __launch_bounds__(256) void part_reduce_kernel(const float* __restrict__ PART,
                                                          float* __restrict__ PART2) {
    constexpr int ROWS = BATCH * SB;
    constexpr int RPG = ROWS / PR;
    int g = blockIdx.x;
    for (int col = threadIdx.x; col < 2 * O; col += 256) {
        float s = 0.f;
        for (int r = 0; r < RPG; ++r)
            s += PART[(size_t)(g * RPG + r) * (2 * O) + col];
        PART2[(size_t)g * (2 * O) + col] = s;
    }
}

template<int O>
__global__ void bnp_kernel(const float* __restrict__ PART2, const float* __restrict__ g,
                           const float* __restrict__ beta, float* __restrict__ bnp) {
    int o = threadIdx.x;
    float s = 0.f, ss = 0.f;
    for (int p = 0; p < PR; ++p) {
        s += PART2[(size_t)p * (2 * O) + o];
        ss += PART2[(size_t)p * (2 * O) + O + o];
    }
    const float cnt = (float)NROWS * (float)KNN;
    float m = s / cnt;
    float var = ss / cnt - m * m;
    float sc = g[o] / sqrtf(var + EPSV);
    bnp[o] = sc;
    bnp[O + o] = beta[o] - m * sc;
}

// ---------------------------------------------------------------- apply (stages 1..3)
template<int O>
__global__ __launch_bounds__(256) void applyb_kernel(const float* __restrict__ HMAX,
                                                     const float* __restrict__ HMIN,
                                                     const float* __restrict__ bnp,
                                                     float* __restrict__ Xn) {
    constexpr int TPR = O / 4;
    int e = blockIdx.x * 256 + threadIdx.x;
    int o = (e % TPR) * 4;
    size_t R = (size_t)(e / TPR) * O + o;
    const float4 hx = *(const float4*)&HMAX[R];
    const float4 hn = *(const float4*)&HMIN[R];
    float4 out;
    { float sc = bnp[o + 0], t = bnp[O + o + 0]; out.x = fmaxf(fmaf(sc, (sc >= 0.f) ? hx.x : hn.x, t), 0.f); }
    { float sc = bnp[o + 1], t = bnp[O + o + 1]; out.y = fmaxf(fmaf(sc, (sc >= 0.f) ? hx.y : hn.y, t), 0.f); }
    { float sc = bnp[o + 2], t = bnp[O + o + 2]; out.z = fmaxf(fmaf(sc, (sc >= 0.f) ? hx.z : hn.z, t), 0.f); }
    { float sc = bnp[o + 3], t = bnp[O + o + 3]; out.w = fmaxf(fmaf(sc, (sc >= 0.f) ? hx.w : hn.w, t), 0.f); }
    *(float4*)&Xn[R] = out;
}

// ---------------------------------------------------------------- stage-4 apply: dense -> point-max -> G0T
__global__ __launch_bounds__(256) void applyb4_kernel(const float* __restrict__ HMAX,
                                                      const float* __restrict__ HMIN,
                                                      const float* __restrict__ bnp,
                                                      float* __restrict__ g0T) {
    constexpr int O = 256;
    constexpr int TPR = O / 4;
    constexpr int RPAR = 256 / TPR;
    constexpr int AB = 32;
    constexpr int RPB = NPTS / AB;
    __shared__ float sh[256 * 4];
    int b = blockIdx.z;
    int otid = threadIdx.x & (TPR - 1);
    int o = otid * 4;
    int rsub = threadIdx.x >> 6;
    int rbase = blockIdx.x * RPB;
    float sc0 = bnp[o + 0], t0 = bnp[O + o + 0];
    float sc1 = bnp[o + 1], t1 = bnp[O + o + 1];
    float sc2 = bnp[o + 2], t2 = bnp[O + o + 2];
    float sc3 = bnp[o + 3], t3 = bnp[O + o + 3];
    float ym0 = 0.f, ym1 = 0.f, ym2 = 0.f, ym3 = 0.f;
    for (int r = rbase + rsub; r < rbase + RPB; r += RPAR) {
        size_t R = (size_t)(b * NPTS + r) * O + o;
        const float4 hx = *(const float4*)&HMAX[R];
        const float4 hn = *(const float4*)&HMIN[R];
        ym0 = fmaxf(ym0, fmaf(sc0, (sc0 >= 0.f) ? hx.x : hn.x, t0));
        ym1 = fmaxf(ym1, fmaf(sc1, (sc1 >= 0.f) ? hx.y : hn.y, t1));
        ym2 = fmaxf(ym2, fmaf(sc2, (sc2 >= 0.f) ? hx.z : hn.z, t2));
        ym3 = fmaxf(ym3, fmaf(sc3, (sc3 >= 0.f) ? hx.w : hn.w, t3));
    }
    float* my = &sh[threadIdx.x * 4];
    my[0] = ym0; my[1] = ym1; my[2] = ym2; my[3] = ym3;
    __syncthreads();
    if (threadIdx.x < TPR) {
        float a0 = ym0, a1 = ym1, a2 = ym2, a3 = ym3;
        for (int g = 1; g < RPAR; ++g) {
            const float* p = &sh[(g * TPR + threadIdx.x) * 4];
            a0 = fmaxf(a0, p[0]); a1 = fmaxf(a1, p[1]);
            a2 = fmaxf(a2, p[2]); a3 = fmaxf(a3, p[3]);
        }
        a0 = fmaxf(a0, 0.f); a1 = fmaxf(a1, 0.f);
        a2 = fmaxf(a2, 0.f); a3 = fmaxf(a3, 0.f);
        atomicMax((int*)&g0T[(o + 0) * 8 + b], __float_as_int(a0));
        atomicMax((int*)&g0T[(o + 1) * 8 + b], __float_as_int(a1));
        atomicMax((int*)&g0T[(o + 2) * 8 + b], __float_as_int(a2));
        atomicMax((int*)&g0T[(o + 3) * 8 + b], __float_as_int(a3));
    }
}

// ---------------------------------------------------------------- point-max of X2/X3 into G0T channels [256,448)
__global__ __launch_bounds__(256) void gmax23_kernel(const float* __restrict__ X2,
                                                     const float* __restrict__ X3,
                                                     float* __restrict__ g0T) {
    int b = blockIdx.x;
    int n0 = blockIdx.y * 32;
    int o = threadIdx.x;
    if (o >= 192) return;
    const float* src; int col, stride, ch;
    if (o < 128) { src = X3; col = o;       stride = 128; ch = 256 + o; }
    else         { src = X2; col = o - 128; stride = 64;  ch = 384 + (o - 128); }
    float m = 0.f;
#pragma unroll 8
    for (int n = n0; n < n0 + 32; ++n)
        m = fmaxf(m, src[((size_t)(b * NPTS + n)) * stride + col]);
    atomicMax((int*)&g0T[ch * 8 + b], __float_as_int(m));
}

// ---------------------------------------------------------------- fc weight transpose
__global__ __launch_bounds__(256) void transpose_kernel(const float* __restrict__ w,
                                                        float* __restrict__ wT, int O, int Cc) {
    int e = blockIdx.x * 256 + threadIdx.x;
    if (e >= O * Cc) return;
    int o = e / Cc, c = e - o * Cc;
    wT[c * O + o] = w[e];
}

// ---------------------------------------------------------------- fc1 + bnf1 + relu
__global__ __launch_bounds__(64) void fc1_kernel(const float* __restrict__ g0T,
                                                 const float* __restrict__ w1T,
                                                 const float* __restrict__ b1,
                                                 const float* __restrict__ bng,
                                                 const float* __restrict__ bnb,
                                                 float* __restrict__ A) {
    int o = blockIdx.x * 64 + threadIdx.x;
    float acc[8] = {};
    for (int c = 0; c < 448; ++c) {
        float wv = w1T[c * 256 + o];
        const float4 h0 = *(const float4*)&g0T[c * 8];
        const float4 h1 = *(const float4*)&g0T[c * 8 + 4];
        acc[0] = fmaf(wv, h0.x, acc[0]); acc[1] = fmaf(wv, h0.y, acc[1]);
        acc[2] = fmaf(wv, h0.z, acc[2]); acc[3] = fmaf(wv, h0.w, acc[3]);
        acc[4] = fmaf(wv, h1.x, acc[4]); acc[5] = fmaf(wv, h1.y, acc[5]);
        acc[6] = fmaf(wv, h1.z, acc[6]); acc[7] = fmaf(wv, h1.w, acc[7]);
    }
    float bb = b1[o];
    float h[8], m = 0.f;
#pragma unroll
    for (int b = 0; b < 8; ++b) { h[b] = acc[b] + bb; m += h[b]; }
    m *= 0.125f;
    float var = 0.f;
#pragma unroll
    for (int b = 0; b < 8; ++b) { float d = h[b] - m; var = fmaf(d, d, var); }
    var *= 0.125f;
    float sc = bng[o] / sqrtf(var + EPSV);
    float t = bnb[o] - m * sc;
#pragma unroll
    for (int b = 0; b < 8; ++b) A[o * 8 + b] = fmaxf(fmaf(sc, h[b], t), 0.f);
}

// ---------------------------------------------------------------- fc2..fc4 tail (one block)
__global__ __launch_bounds__(256) void tail_kernel(const float* __restrict__ A,
                                                   const float* __restrict__ w2T, const float* __restrict__ b2,
                                                   const float* __restrict__ g2, const float* __restrict__ be2,
                                                   const float* __restrict__ w3T, const float* __restrict__ b3,
                                                   const float* __restrict__ g3, const float* __restrict__ be3,
                                                   const float* __restrict__ w4, const float* __restrict__ b4,
                                                   float* __restrict__ out) {
    __shared__ __align__(16) float B2[128 * 8];
    __shared__ __align__(16) float C3[16 * 8];
    int tid = threadIdx.x;
    if (tid < 128) {
        int o = tid;
        float acc[8] = {};
        for (int c = 0; c < 256; ++c) {
            float wv = w2T[c * 128 + o];
            const float4 a0 = *(const float4*)&A[c * 8];
            const float4 a1 = *(const float4*)&A[c * 8 + 4];
            acc[0] = fmaf(wv, a0.x, acc[0]); acc[1] = fmaf(wv, a0.y, acc[1]);
            acc[2] = fmaf(wv, a0.z, acc[2]); acc[3] = fmaf(wv, a0.w, acc[3]);
            acc[4] = fmaf(wv, a1.x, acc[4]); acc[5] = fmaf(wv, a1.y, acc[5]);
            acc[6] = fmaf(wv, a1.z, acc[6]); acc[7] = fmaf(wv, a1.w, acc[7]);
        }
        float bb = b2[o];
        float h[8], m = 0.f;
#pragma unroll
        for (int b = 0; b < 8; ++b) { h[b] = acc[b] + bb; m += h[b]; }
        m *= 0.125f;
        float var = 0.f;
#pragma unroll
        for (int b = 0; b < 8; ++b) { float d = h[b] - m; var = fmaf(d, d, var); }
        var *= 0.125f;
        float sc = g2[o] / sqrtf(var + EPSV);
        float t = be2[o] - m * sc;
#pragma unroll
        for (int b = 0; b < 8; ++b) B2[o * 8 + b] = fmaxf(fmaf(sc, h[b], t), 0.f);
    }
    __syncthreads();
    if (tid < 16) {
        int o = tid;
        float acc[8] = {};
        for (int c = 0; c < 128; ++c) {
            float wv = w3T[c * 16 + o];
            const float4 a0 = *(const float4*)&B2[c * 8];
            const float4 a1 = *(const float4*)&B2[c * 8 + 4];
            acc[0] = fmaf(wv, a0.x, acc[0]); acc[1] = fmaf(wv, a0.y, acc[1]);
            acc[2] = fmaf(wv, a0.z, acc[2]); acc[3] = fmaf(wv, a0.w, acc[3]);
            acc[4] = fmaf(wv, a1.x, acc[4]); acc[5] = fmaf(wv, a1.y, acc[5]);
            acc[6] = fmaf(wv, a1.z, acc[6]); acc[7] = fmaf(wv, a1.w, acc[7]);
        }
        float bb = b3[o];
        float h[8], m = 0.f;
#pragma unroll
        for (int b = 0; b < 8; ++b) { h[b] = acc[b] + bb; m += h[b]; }
        m *= 0.125f;
        float var = 0.f;
#pragma unroll
        for (int b = 0; b < 8; ++b) { float d = h[b] - m; var = fmaf(d, d, var); }
        var *= 0.125f;
        float sc = g3[o] / sqrtf(var + EPSV);
        float t = be3[o] - m * sc;
#pragma unroll
        for (int b = 0; b < 8; ++b) C3[o * 8 + b] = fmaxf(fmaf(sc, h[b], t), 0.f);
    }
    __syncthreads();
    if (tid < 8) {
        int b = tid;
        float acc = b4[0];
#pragma unroll
        for (int c = 0; c < 16; ++c) acc = fmaf(w4[c], C3[c * 8 + b], acc);
        out[b] = acc;
    }
}

// ================================================================ host side
struct Arena {
    char* base; size_t off, cap; bool ok;
    Arena(void* b, size_t c) : base((char*)b), off(0), cap(c), ok(true) {}
    void* get(size_t bytes) {
        char* p = base + off;
        off += (bytes + 255) & ~(size_t)255;
        if (off > cap) ok = false;
        return p;
    }
};

// one EdgeConv stage, output stored to Xout (stages 1..3)
template<int C, int O>
static void run_stage(const float* Xin, float* Xout, const float* W, const float* bias,
                      const float* g, const float* be, float* SCRBIG, float* UVA,
                      u16* XPH, u16* XPL, u16* WPH, u16* WPL, u64* CANDB,
                      u16* IDX, float* SQ, float* PART, float* PART2, float* BNP, hipStream_t s) {
    dim3 blk(256);
    float* HMAX = SCRBIG;
    float* HMIN = SCRBIG + (size_t)NROWS * O;
    sqnorm_kernel<C><<<NROWS / 256, blk, 0, s>>>(Xin, SQ);
    if constexpr (C >= 32) {
        split_pack_kernel<C><<<NROWS * C / 8 / 256, blk, 0, s>>>(Xin, XPH, XPL);
        knn_kernel<C><<<dim3(2, NPTS / 64, BATCH), blk, 0, s>>>(XPH, XPL, SQ, CANDB);
        knn_merge_kernel<<<dim3(NPTS / 4, 1, BATCH), blk, 0, s>>>(CANDB, IDX);
        wsplit_pack_kernel<C, O><<<(2 * O * C / 8 + 255) / 256, blk, 0, s>>>(W, WPH, WPL);
        uvb_mfma_kernel<C, O><<<dim3(2 * O / 64, NPTS / 64, BATCH), blk, 0, s>>>(XPH, XPL, WPH, WPL, bias, UVA);
    } else {
        // stage 1: EXACT f32 distances (3-D near-ties are below split-bf16 error)
        for (int b0 = 0; b0 < BATCH; b0 += 4) {
            dist_gemm_kernel<C><<<dim3(NPTS / 64, NPTS / 64, 4), blk, 0, s>>>(Xin, SCRBIG, b0);
            topk_kernel<<<dim3(NPTS / 4, 1, 4), blk, 0, s>>>(SCRBIG, SQ, IDX, b0);
        }
        uvb_gemm_kernel<C, O><<<dim3(2 * O / 64, NPTS / 64, BATCH), blk, 0, s>>>(Xin, W, bias, UVA);
    }
    statsb_kernel<O><<<dim3(SB, 1, BATCH), blk, 0, s>>>(UVA, IDX, PART, HMAX, HMIN);
    part_reduce_kernel<O><<<PR, blk, 0, s>>>(PART, PART2);
    bnp_kernel<O><<<1, O, 0, s>>>(PART2, g, be, BNP);
    applyb_kernel<O><<<NROWS * (O / 4) / 256, blk, 0, s>>>(HMAX, HMIN, BNP, Xout);
}

// stage 4
static void run_stage4(const float* Xin, const float* W, const float* bias,
                       const float* g, const float* be, float* SCRBIG, float* UVA,
                       u16* XPH, u16* XPL, u16* WPH, u16* WPL, u64* CANDB,
                       u16* IDX, float* SQ, float* PART, float* PART2, float* BNP, float* G0T,
                       hipStream_t s) {
    constexpr int C = 128;
    dim3 blk(256);
    float* HMAX = SCRBIG;
    float* HMIN = SCRBIG + (size_t)NROWS * 256;
    sqnorm_kernel<C><<<NROWS / 256, blk, 0, s>>>(Xin, SQ);
    split_pack_kernel<C><<<NROWS * C / 8 / 256, blk, 0, s>>>(Xin, XPH, XPL);
    knn_kernel<C><<<dim3(2, NPTS / 64, BATCH), blk, 0, s>>>(XPH, XPL, SQ, CANDB);
    knn_merge_kernel<<<dim3(NPTS / 4, 1, BATCH), blk, 0, s>>>(CANDB, IDX);
    wsplit_pack_kernel<C, 256><<<(512 * C / 8 + 255) / 256, blk, 0, s>>>(W, WPH, WPL);
    uvb_mfma_kernel<C, 256><<<dim3(8, NPTS / 64, BATCH), blk, 0, s>>>(XPH, XPL, WPH, WPL, bias, UVA);
    statsb_kernel<256><<<dim3(SB, 1, BATCH), blk, 0, s>>>(UVA, IDX, PART, HMAX, HMIN);
    part_reduce_kernel<256><<<PR, blk, 0, s>>>(PART, PART2);
    bnp_kernel<256><<<1, 256, 0, s>>>(PART2, g, be, BNP);
    fill_zero_kernel<<<14, blk, 0, s>>>(G0T, 448 * 8);
    applyb4_kernel<<<dim3(32, 1, BATCH), blk, 0, s>>>(HMAX, HMIN, BNP, G0T);
}

extern "C" void kernel_launch(void* const* d_in, const int* in_sizes, int n_in,
                              void* d_out, int out_size, void* d_ws, size_t ws_size,
                              hipStream_t stream) {
    float* out = (float*)d_out;
    if (n_in < 31) { diag_kernel<<<1, 64, 0, stream>>>(out, 9000.f); return; }

    const float* x       = (const float*)d_in[0];
    const float* cw[4]   = {(const float*)d_in[1], (const float*)d_in[5], (const float*)d_in[9],  (const float*)d_in[13]};
    const float* cb[4]   = {(const float*)d_in[2], (const float*)d_in[6], (const float*)d_in[10], (const float*)d_in[14]};
    const float* bg[4]   = {(const float*)d_in[3], (const float*)d_in[7], (const float*)d_in[11], (const float*)d_in[15]};
    const float* bb[4]   = {(const float*)d_in[4], (const float*)d_in[8], (const float*)d_in[12], (const float*)d_in[16]};
    const float* fc1_w = (const float*)d_in[17]; const float* fc1_b = (const float*)d_in[18];
    const float* bnf1_g = (const float*)d_in[19]; const float* bnf1_b = (const float*)d_in[20];
    const float* fc2_w = (const float*)d_in[21]; const float* fc2_b = (const float*)d_in[22];
    const float* bnf2_g = (const float*)d_in[23]; const float* bnf2_b = (const float*)d_in[24];
    const float* fc3_w = (const float*)d_in[25]; const float* fc3_b = (const float*)d_in[26];
    const float* bnf3_g = (const float*)d_in[27]; const float* bnf3_b = (const float*)d_in[28];
    const float* fc4_w = (const float*)d_in[29]; const float* fc4_b = (const float*)d_in[30];

    Arena ar(d_ws, ws_size);
    float* X1 = (float*)ar.get((size_t)NROWS * 64 * 4);
    float* X2 = (float*)ar.get((size_t)NROWS * 64 * 4);
    float* X3 = (float*)ar.get((size_t)NROWS * 128 * 4);
    u16* IDX = (u16*)ar.get((size_t)NROWS * KNN * 2);
    float* SQ = (float*)ar.get((size_t)NROWS * 4);
    float* PART = (float*)ar.get((size_t)BATCH * SB * 512 * 4);
    float* PART2 = (float*)ar.get((size_t)PR * 512 * 4);
    float* BNP = (float*)ar.get(512 * 4);
    float* G0T = (float*)ar.get(448 * 8 * 4);
    float* ABUF = (float*)ar.get(256 * 8 * 4);
    u16* XPH = (u16*)ar.get((size_t)NROWS * 128 * 2);
    u16* XPL = (u16*)ar.get((size_t)NROWS * 128 * 2);
    u16* WPH = (u16*)ar.get(512 * 128 * 2);
    u16* WPL = (u16*)ar.get(512 * 128 * 2);
    u64* CANDB = (u64*)ar.get((size_t)NROWS * 40 * 8);            // 5.25 MB
    float* SCRBIG = (float*)ar.get((size_t)4 * NPTS * NPTS * 4);  // stage1 DIST x4 / HMAX+HMIN+UVA / W-transposes
    if (!ar.ok) {
        diag_kernel<<<1, 64, 0, stream>>>(out, 3000.f + (float)(ws_size >> 20));
        return;
    }
    float* UVA = SCRBIG + (size_t)2 * NPTS * NPTS;

    dim3 blk(256);
    run_stage<3, 64>(x, X1, cw[0], cb[0], bg[0], bb[0], SCRBIG, UVA, XPH, XPL, WPH, WPL, CANDB, IDX, SQ, PART, PART2, BNP, stream);
    run_stage<64, 64>(X1, X2, cw[1], cb[1], bg[1], bb[1], SCRBIG, UVA, XPH, XPL, WPH, WPL, CANDB, IDX, SQ, PART, PART2, BNP, stream);
    run_stage<64, 128>(X2, X3, cw[2], cb[2], bg[2], bb[2], SCRBIG, UVA, XPH, XPL, WPH, WPL, CANDB, IDX, SQ, PART, PART2, BNP, stream);
    run_stage4(X3, cw[3], cb[3], bg[3], bb[3], SCRBIG, UVA, XPH, XPL, WPH, WPL, CANDB, IDX, SQ, PART, PART2, BNP, G0T, stream);

    gmax23_kernel<<<dim3(BATCH, 64), blk, 0, stream>>>(X2, X3, G0T);

    float* W1T = SCRBIG;
    float* W2T = W1T + 448 * 256;
    float* W3T = W2T + 256 * 128;
    transpose_kernel<<<(256 * 448 + 255) / 256, blk, 0, stream>>>(fc1_w, W1T, 256, 448);
    transpose_kernel<<<(128 * 256 + 255) / 256, blk, 0, stream>>>(fc2_w, W2T, 128, 256);
    transpose_kernel<<<(16 * 128 + 255) / 256, blk, 0, stream>>>(fc3_w, W3T, 16, 128);
    fc1_kernel<<<4, 64, 0, stream>>>(G0T, W1T, fc1_b, bnf1_g, bnf1_b, ABUF);
    tail_kernel<<<1, 256, 0, stream>>>(ABUF, W2T, fc2_b, bnf2_g, bnf2_b,
                                       W3T, fc3_b, bnf3_g, bnf3_b, fc4_w, fc4_b, out);
}

// Round 16
// 718.189 us; speedup vs baseline: 1.2098x; 1.2098x over previous
//
#include <hip/hip_runtime.h>
#include <hip/hip_bf16.h>
#include <cfloat>

constexpr int BATCH = 8, NPTS = 2048, KNN = 20;
constexpr int NROWS = BATCH * NPTS;
constexpr float EPSV = 1e-5f;
constexpr int SB = 256;                          // statsb blocks per batch
constexpr int PR = 64;                           // reduced partials
constexpr int RBB = NPTS / 16;                   // row-blocks per batch (128)
constexpr int KC2 = 48;                          // knn per-row candidate cap (per 512-col chunk)
constexpr int QCAP = 512;                        // stage-1 topk queue cap
constexpr int NCH = 4;                           // knn col chunks (512 cols each)

using u16 = unsigned short;
using u64 = unsigned long long;
typedef __attribute__((ext_vector_type(8))) short short8;
typedef __attribute__((ext_vector_type(4))) float f32x4;

// ---------------------------------------------------------------- diag / fill
__global__ void diag_kernel(float* out, float v) {
    if (threadIdx.x < 8) out[threadIdx.x] = v;
}

__global__ __launch_bounds__(256) void fill_zero_kernel(float* __restrict__ p, int n) {
    int i = blockIdx.x * 256 + threadIdx.x;
    if (i < n) p[i] = 0.f;
}

// ---------------------------------------------------------------- sqnorm over all rows
template<int C>
__global__ __launch_bounds__(256) void sqnorm_kernel(const float* __restrict__ X,
                                                     float* __restrict__ sq) {
    int r = blockIdx.x * 256 + threadIdx.x;
    const float* x = X + (size_t)r * C;
    float s = 0.f;
#pragma unroll
    for (int c = 0; c < C; ++c) { float v = x[c]; s = fmaf(v, v, s); }
    sq[r] = s;
}

// ---------------------------------------------------------------- split X -> hi/lo bf16 in PACKED MFMA-fragment layout
template<int C>
__global__ __launch_bounds__(256) void split_pack_kernel(const float* __restrict__ X,
                                                         u16* __restrict__ XPH,
                                                         u16* __restrict__ XPL) {
    constexpr int KB = C / 32;
    int e = blockIdx.x * 256 + threadIdx.x;     // one short8 fragment per thread
    int lane = e & 63;
    int rest = e >> 6;
    int kb = rest % KB;
    int Rb = rest / KB;
    int row = Rb * 16 + (lane & 15);
    int col = kb * 32 + (lane >> 4) * 8;
    const float* src = &X[(size_t)row * C + col];
    u16 h[8], l[8];
#pragma unroll
    for (int q = 0; q < 8; ++q) {
        float v = src[q];
        __hip_bfloat16 hb = __float2bfloat16(v);
        float hf = __bfloat162float(hb);
        __hip_bfloat16 lb = __float2bfloat16(v - hf);
        h[q] = *(u16*)&hb; l[q] = *(u16*)&lb;
    }
    u16* dh = &XPH[(size_t)e * 8];
    u16* dl = &XPL[(size_t)e * 8];
#pragma unroll
    for (int q = 0; q < 8; ++q) { dh[q] = h[q]; dl[q] = l[q]; }
}

// ---------------------------------------------------------------- split W -> packed hi/lo (n<O: W1; n>=O: W2-W1)
template<int C, int O>
__global__ __launch_bounds__(256) void wsplit_pack_kernel(const float* __restrict__ W,
                                                          u16* __restrict__ WPH,
                                                          u16* __restrict__ WPL) {
    constexpr int KB = C / 32;
    constexpr int NFRAG = (2 * O / 16) * KB * 64;
    int e = blockIdx.x * 256 + threadIdx.x;
    if (e >= NFRAG) return;
    int lane = e & 63;
    int rest = e >> 6;
    int kb = rest % KB;
    int Nb = rest / KB;
    int n = Nb * 16 + (lane & 15);
    int col = kb * 32 + (lane >> 4) * 8;
    u16 h[8], l[8];
#pragma unroll
    for (int q = 0; q < 8; ++q) {
        int c = col + q;
        float wv = (n < O) ? W[(size_t)n * (2 * C) + c]
                           : W[(size_t)(n - O) * (2 * C) + C + c] - W[(size_t)(n - O) * (2 * C) + c];
        __hip_bfloat16 hb = __float2bfloat16(wv);
        float hf = __bfloat162float(hb);
        __hip_bfloat16 lb = __float2bfloat16(wv - hf);
        h[q] = *(u16*)&hb; l[q] = *(u16*)&lb;
    }
    u16* dh = &WPH[(size_t)e * 8];
    u16* dl = &WPL[(size_t)e * 8];
#pragma unroll
    for (int q = 0; q < 8; ++q) { dh[q] = h[q]; dl[q] = l[q]; }
}

// ---------------------------------------------------------------- wave-64 bitonic sorts
__device__ __forceinline__ float bitonic64_desc_f32(float key, int lane) {
#pragma unroll
    for (int k = 2; k <= 64; k <<= 1) {
#pragma unroll
        for (int j = k >> 1; j > 0; j >>= 1) {
            float p = __shfl_xor(key, j);
            bool keepMax = (((lane & j) == 0) == ((lane & k) == 0));
            key = ((key > p) == keepMax) ? key : p;
        }
    }
    return key;
}

__device__ __forceinline__ u64 bitonic64_desc_u64(u64 key, int lane) {
#pragma unroll
    for (int k = 2; k <= 64; k <<= 1) {
#pragma unroll
        for (int j = k >> 1; j > 0; j >>= 1) {
            u64 p = __shfl_xor(key, j);
            bool keepMax = (((lane & j) == 0) == ((lane & k) == 0));
            key = ((key > p) == keepMax) ? key : p;
        }
    }
    return key;
}

// ---------------------------------------------------------------- f32 dist GEMM (stage 1, exact; z = batch chunk)
template<int C>
__global__ __launch_bounds__(256) void dist_gemm_kernel(const float* __restrict__ X,
                                                        float* __restrict__ D, int b0) {
    constexpr int KC = (C < 32) ? C : 32;
    __shared__ __align__(16) float As[KC][68];
    __shared__ __align__(16) float Bs[KC][68];
    int b = b0 + blockIdx.z;
    int i0 = blockIdx.y * 64, j0 = blockIdx.x * 64;
    const float* Xb = X + (size_t)b * NPTS * C;
    int tx = threadIdx.x & 15, ty = threadIdx.x >> 4;
    float acc[4][4] = {};
    for (int c0 = 0; c0 < C; c0 += KC) {
        for (int t = threadIdx.x; t < 64 * KC; t += 256) {
            int i = t / KC, c = t % KC;
            As[c][i] = Xb[(size_t)(i0 + i) * C + c0 + c];
            Bs[c][i] = Xb[(size_t)(j0 + i) * C + c0 + c];
        }
        __syncthreads();
#pragma unroll
        for (int c = 0; c < KC; ++c) {
            const float4 av = *(const float4*)&As[c][ty * 4];
            const float4 bv = *(const float4*)&Bs[c][tx * 4];
            float ar[4] = {av.x, av.y, av.z, av.w};
            float br[4] = {bv.x, bv.y, bv.z, bv.w};
#pragma unroll
            for (int r = 0; r < 4; ++r)
#pragma unroll
                for (int q = 0; q < 4; ++q) acc[r][q] = fmaf(ar[r], br[q], acc[r][q]);
        }
        __syncthreads();
    }
    float* Dz = D + (size_t)blockIdx.z * NPTS * NPTS;
#pragma unroll
    for (int r = 0; r < 4; ++r) {
        float4 o4 = make_float4(acc[r][0], acc[r][1], acc[r][2], acc[r][3]);
        *(float4*)&Dz[(size_t)(i0 + ty * 4 + r) * NPTS + j0 + tx * 4] = o4;
    }
}

// ---------------------------------------------------------------- stage-1 top-k from materialized D (exact)
__global__ __launch_bounds__(256) void topk_kernel(const float* __restrict__ D,
                                                   const float* __restrict__ sq,
                                                   u16* __restrict__ idx_out, int b0) {
    __shared__ u64 qkey[4][QCAP];
    __shared__ int qn[4];
    int b = b0 + blockIdx.z;
    int w = threadIdx.x >> 6, lane = threadIdx.x & 63;
    int i = blockIdx.x * 4 + w;
    const float* Drow = D + ((size_t)blockIdx.z * NPTS + i) * NPTS;
    const float* sqb = sq + b * NPTS;
    float sqi = sqb[i];
    if (lane == 0) qn[w] = 0;

    float vals[32];
    float mx = -FLT_MAX;
#pragma unroll
    for (int t = 0; t < 8; ++t) {
        int j = t * 256 + lane * 4;
        float4 v4 = *(const float4*)&Drow[j];
        float4 s4 = *(const float4*)&sqb[j];
        float a0 = (2.f * v4.x - sqi - s4.x) + 0.f;
        float a1 = (2.f * v4.y - sqi - s4.y) + 0.f;
        float a2 = (2.f * v4.z - sqi - s4.z) + 0.f;
        float a3 = (2.f * v4.w - sqi - s4.w) + 0.f;
        vals[t * 4 + 0] = a0; vals[t * 4 + 1] = a1;
        vals[t * 4 + 2] = a2; vals[t * 4 + 3] = a3;
        mx = fmaxf(mx, fmaxf(fmaxf(a0, a1), fmaxf(a2, a3)));
    }

    float sm = bitonic64_desc_f32(mx, lane);
    float T0 = __shfl(sm, 19);

#pragma unroll
    for (int t = 0; t < 32; ++t) {
        float v = vals[t];
        if (v >= T0) {
            unsigned j = (unsigned)((t >> 2) * 256 + lane * 4 + (t & 3));
            unsigned bu = __float_as_uint(v);
            unsigned u = (bu & 0x80000000u) ? ~bu : (bu | 0x80000000u);
            u64 key = ((u64)u << 32) | (u64)(0xFFFFFFFFu - j);
            int slot = atomicAdd(&qn[w], 1);
            if (slot < QCAP) qkey[w][slot] = key;
        }
    }
    int C = qn[w];
    if (C > QCAP) C = QCAP;

    u64 key = (lane < C) ? qkey[w][lane] : 0ull;
    key = bitonic64_desc_u64(key, lane);
    int base = 64;
    while (base < C) {
        if (lane >= 20) {
            int src = base + (lane - 20);
            key = (src < C) ? qkey[w][src] : 0ull;
        }
        key = bitonic64_desc_u64(key, lane);
        base += 44;
    }
    if (lane < 20) {
        unsigned j = 0xFFFFFFFFu - (unsigned)(key & 0xFFFFFFFFull);
        idx_out[(size_t)(b * NPTS + i) * KNN + lane] = (u16)j;
    }
}

// ---------------------------------------------------------------- fused kNN (stages 2..4): single pass, D staged in LDS
// block = 16 rows x 512-col chunk; MFMA writes neg-dist to LDS; per-row exact top-20 via
// 20th-lane-max threshold (provable lower bound) + compact + bitonic select.
template<int C>
__global__ __launch_bounds__(256) void knn_kernel(const u16* __restrict__ XPH,
                                                  const u16* __restrict__ XPL,
                                                  const float* __restrict__ SQ,
                                                  u64* __restrict__ CAND) {
    constexpr int KB = C / 32;
    __shared__ float Dl[16][516];
    __shared__ u64 cand[16][KC2];
    __shared__ int cnt[16];
    int b = blockIdx.z;
    int chunk = blockIdx.x;                      // 0..3 (512 cols each)
    int i0 = blockIdx.y * 16;                    // grid.y = 128
    int w = threadIdx.x >> 6, lane = threadIdx.x & 63;
    int l15 = lane & 15, g = lane >> 4;
    size_t base = (size_t)b * RBB * KB * 512;
    const float* sqb = SQ + b * NPTS;

    if (threadIdx.x < 16) cnt[threadIdx.x] = 0;

    // A fragments for this 16-row block (all waves identical; L1/L2-served)
    int Rba = i0 / 16;
    short8 ahi[KB], alo[KB];
#pragma unroll
    for (int kb = 0; kb < KB; ++kb) {
        size_t ia = base + ((size_t)(Rba * KB + kb) * 64 + lane) * 8;
        ahi[kb] = *(const short8*)&XPH[ia];
        alo[kb] = *(const short8*)&XPL[ia];
    }
    float sqr[4];
#pragma unroll
    for (int r = 0; r < 4; ++r) sqr[r] = sqb[i0 + g * 4 + r];

    // MFMA phase: 32 col-blocks; wave w handles c = w + 4t
#pragma unroll
    for (int t = 0; t < 8; ++t) {
        int c = w + 4 * t;
        int Cb = chunk * 32 + c;
        f32x4 acc = {0.f, 0.f, 0.f, 0.f};
#pragma unroll
        for (int kb = 0; kb < KB; ++kb) {
            size_t ib = base + ((size_t)(Cb * KB + kb) * 64 + lane) * 8;
            short8 bhi = *(const short8*)&XPH[ib];
            short8 blo = *(const short8*)&XPL[ib];
            acc = __builtin_amdgcn_mfma_f32_16x16x32_bf16(ahi[kb], bhi, acc, 0, 0, 0);
            acc = __builtin_amdgcn_mfma_f32_16x16x32_bf16(ahi[kb], blo, acc, 0, 0, 0);
            acc = __builtin_amdgcn_mfma_f32_16x16x32_bf16(alo[kb], bhi, acc, 0, 0, 0);
        }
        int colg = Cb * 16 + l15;
        float sqc = sqb[colg];
        int cl = c * 16 + l15;
#pragma unroll
        for (int r = 0; r < 4; ++r)
            Dl[g * 4 + r][cl] = (2.f * acc[r] - sqr[r] - sqc) + 0.f;
    }
    __syncthreads();

    // selection: wave w owns rows w*4 .. w*4+3
    for (int rr = 0; rr < 4; ++rr) {
        int row = w * 4 + rr;
        float vv[8];
        float mx = -FLT_MAX;
#pragma unroll
        for (int q = 0; q < 8; ++q) {
            vv[q] = Dl[row][lane + 64 * q];
            mx = fmaxf(mx, vv[q]);
        }
        float sv = bitonic64_desc_f32(mx, lane);
        float T = __shfl(sv, 19);                // 20th lane-max <= true v20 (20 distinct cols >= T)
#pragma unroll
        for (int q = 0; q < 8; ++q) {
            float v = vv[q];
            if (v >= T) {
                unsigned colg = (unsigned)(chunk * 512 + lane + 64 * q);
                unsigned bu = __float_as_uint(v);
                unsigned u = (bu & 0x80000000u) ? ~bu : (bu | 0x80000000u);
                u64 key = ((u64)u << 32) | (u64)(0xFFFFFFFFu - colg);
                int slot = atomicAdd(&cnt[row], 1);
                if (slot < KC2) cand[row][slot] = key;
            }
        }
        int Cn = cnt[row]; if (Cn > KC2) Cn = KC2;
        u64 key = (lane < Cn) ? cand[row][lane] : 0ull;
        key = bitonic64_desc_u64(key, lane);
        if (lane < 20)
            CAND[(((size_t)(b * NPTS + i0 + row)) * NCH + chunk) * 20 + lane] = key;
    }
}

// ---------------------------------------------------------------- merge chunk top-20s (NCH*20 = 80) -> IDX (one wave per row)
__global__ __launch_bounds__(256) void knn_merge_kernel(const u64* __restrict__ CAND,
                                                        u16* __restrict__ idx_out) {
    int b = blockIdx.z;
    int w = threadIdx.x >> 6, lane = threadIdx.x & 63;
    int i = blockIdx.x * 4 + w;
    size_t rb = ((size_t)(b * NPTS + i)) * (NCH * 20);
    u64 key = CAND[rb + lane];                   // first 64 of 80
    key = bitonic64_desc_u64(key, lane);
    u64 extra = (lane >= 20 && lane < 36) ? CAND[rb + 64 + (lane - 20)] : 0ull;
    if (lane >= 20) key = extra;                 // keep top-20, bring in last 16
    key = bitonic64_desc_u64(key, lane);
    if (lane < 20) {
        unsigned j = 0xFFFFFFFFu - (unsigned)(key & 0xFFFFFFFFull);
        idx_out[((size_t)(b * NPTS + i)) * KNN + lane] = (u16)j;
    }
}

// ---------------------------------------------------------------- uvb via MFMA from packed fragments
template<int C, int O>
__global__ __launch_bounds__(256) void uvb_mfma_kernel(const u16* __restrict__ XPH,
                                                       const u16* __restrict__ XPL,
                                                       const u16* __restrict__ WPH,
                                                       const u16* __restrict__ WPL,
                                                       const float* __restrict__ bias,
                                                       float* __restrict__ UVA) {
    constexpr int KB = C / 32;
    int b = blockIdx.z;
    int r0 = blockIdx.y * 64, n0 = blockIdx.x * 64;
    int w = threadIdx.x >> 6, lane = threadIdx.x & 63;
    int l15 = lane & 15, g = lane >> 4;
    size_t base = (size_t)b * RBB * KB * 512;
    int Rba = r0 / 16 + w;
    short8 ahi[KB], alo[KB];
#pragma unroll
    for (int kb = 0; kb < KB; ++kb) {
        size_t ia = base + ((size_t)(Rba * KB + kb) * 64 + lane) * 8;
        ahi[kb] = *(const short8*)&XPH[ia];
        alo[kb] = *(const short8*)&XPL[ia];
    }
    float* UVb = UVA + (size_t)b * NPTS * 2 * O;
#pragma unroll
    for (int nt = 0; nt < 4; ++nt) {
        int Nb = n0 / 16 + nt;
        f32x4 acc = {0.f, 0.f, 0.f, 0.f};
#pragma unroll
        for (int kb = 0; kb < KB; ++kb) {
            size_t ib = ((size_t)(Nb * KB + kb) * 64 + lane) * 8;
            short8 bhi = *(const short8*)&WPH[ib];
            short8 blo = *(const short8*)&WPL[ib];
            acc = __builtin_amdgcn_mfma_f32_16x16x32_bf16(ahi[kb], bhi, acc, 0, 0, 0);
            acc = __builtin_amdgcn_mfma_f32_16x16x32_bf16(ahi[kb], blo, acc, 0, 0, 0);
            acc = __builtin_amdgcn_mfma_f32_16x16x32_bf16(alo[kb], bhi, acc, 0, 0, 0);
        }
        int n = n0 + nt * 16 + l15;
        float badd = (n >= O) ? bias[n - O] : 0.f;
        int rbase = r0 + w * 16 + g * 4;
#pragma unroll
        for (int r = 0; r < 4; ++r)
            UVb[(size_t)(rbase + r) * (2 * O) + n] = acc[r] + badd;
    }
}

// ---------------------------------------------------------------- f32 uvb (stage 1, C=3)
template<int C, int O>
__global__ __launch_bounds__(256) void uvb_gemm_kernel(const float* __restrict__ X,
                                                       const float* __restrict__ W,
                                                       const float* __restrict__ bias,
                                                       float* __restrict__ UVA) {
    constexpr int KC = (C < 32) ? C : 32;
    __shared__ __align__(16) float As[KC][68];
    __shared__ __align__(16) float Bs[KC][68];
    int b = blockIdx.z;
    int r0 = blockIdx.y * 64, n0 = blockIdx.x * 64;
    int tx = threadIdx.x & 15, ty = threadIdx.x >> 4;
    float acc[4][4] = {};
    for (int c0 = 0; c0 < C; c0 += KC) {
        for (int t = threadIdx.x; t < 64 * KC; t += 256) {
            int i = t / KC, c = t % KC;
            As[c][i] = X[(size_t)(b * NPTS + r0 + i) * C + c0 + c];
            int n = n0 + i;
            float wv;
            if (n < O) wv = W[(size_t)n * (2 * C) + c0 + c];
            else {
                int o = n - O;
                wv = W[(size_t)o * (2 * C) + C + c0 + c] - W[(size_t)o * (2 * C) + c0 + c];
            }
            Bs[c][i] = wv;
        }
        __syncthreads();
#pragma unroll
        for (int c = 0; c < KC; ++c) {
            const float4 av = *(const float4*)&As[c][ty * 4];
            const float4 bv = *(const float4*)&Bs[c][tx * 4];
            float ar[4] = {av.x, av.y, av.z, av.w};
            float br[4] = {bv.x, bv.y, bv.z, bv.w};
#pragma unroll
            for (int r = 0; r < 4; ++r)
#pragma unroll
                for (int q = 0; q < 4; ++q) acc[r][q] = fmaf(ar[r], br[q], acc[r][q]);
        }
        __syncthreads();
    }
    float badd[4] = {0.f, 0.f, 0.f, 0.f};
    if (n0 >= O) {
#pragma unroll
        for (int q = 0; q < 4; ++q) badd[q] = bias[n0 - O + tx * 4 + q];
    }
    float* UVb = UVA + (size_t)b * NPTS * 2 * O;
#pragma unroll
    for (int r = 0; r < 4; ++r) {
        float4 o4 = make_float4(acc[r][0] + badd[0], acc[r][1] + badd[1],
                                acc[r][2] + badd[2], acc[r][3] + badd[3]);
        *(float4*)&UVb[(size_t)(r0 + ty * 4 + r) * (2 * O) + n0 + tx * 4] = o4;
    }
}

// ---------------------------------------------------------------- stats: ONE gather pass -> block partials + dense HMAX/HMIN
template<int O>
__global__ __launch_bounds__(256) void statsb_kernel(const float* __restrict__ UVA,
                                                     const u16* __restrict__ idx,
                                                     float* __restrict__ PART,
                                                     float* __restrict__ HMAX,
                                                     float* __restrict__ HMIN) {
    constexpr int TPR = O / 4;
    constexpr int RPAR = 256 / TPR;
    constexpr int RPB = NPTS / SB;
    __shared__ float sh[256 * 8];
    int b = blockIdx.z;
    const float* UVb = UVA + (size_t)b * NPTS * 2 * O;
    int otid = threadIdx.x % TPR;
    int o = otid * 4;
    int rsub = threadIdx.x / TPR;
    int rbase = blockIdx.x * RPB;
    float s0 = 0, s1 = 0, s2 = 0, s3 = 0, q0 = 0, q1 = 0, q2 = 0, q3 = 0;
    for (int r = rbase + rsub; r < rbase + RPB; r += RPAR) {
        const float4 v4 = *(const float4*)&UVb[(size_t)r * (2 * O) + O + o];
        const u16* ix = idx + (size_t)(b * NPTS + r) * KNN;
        float mx0 = -FLT_MAX, mx1 = -FLT_MAX, mx2 = -FLT_MAX, mx3 = -FLT_MAX;
        float mn0 = FLT_MAX, mn1 = FLT_MAX, mn2 = FLT_MAX, mn3 = FLT_MAX;
#pragma unroll
        for (int k = 0; k < KNN; ++k) {
            int j = (int)ix[k] & (NPTS - 1);
            const float4 u4 = *(const float4*)&UVb[(size_t)j * (2 * O) + o];
            float h0 = u4.x + v4.x, h1 = u4.y + v4.y, h2 = u4.z + v4.z, h3 = u4.w + v4.w;
            s0 += h0; q0 = fmaf(h0, h0, q0); mx0 = fmaxf(mx0, h0); mn0 = fminf(mn0, h0);
            s1 += h1; q1 = fmaf(h1, h1, q1); mx1 = fmaxf(mx1, h1); mn1 = fminf(mn1, h1);
            s2 += h2; q2 = fmaf(h2, h2, q2); mx2 = fmaxf(mx2, h2); mn2 = fminf(mn2, h2);
            s3 += h3; q3 = fmaf(h3, h3, q3); mx3 = fmaxf(mx3, h3); mn3 = fminf(mn3, h3);
        }
        size_t R = (size_t)(b * NPTS + r) * O + o;
        *(float4*)&HMAX[R] = make_float4(mx0, mx1, mx2, mx3);
        *(float4*)&HMIN[R] = make_float4(mn0, mn1, mn2, mn3);
    }
    float* my = &sh[threadIdx.x * 8];
    my[0] = s0; my[1] = s1; my[2] = s2; my[3] = s3;
    my[4] = q0; my[5] = q1; my[6] = q2; my[7] = q3;
    __syncthreads();
    if (threadIdx.x < TPR) {
        float a[8];
#pragma unroll
        for (int c = 0; c < 8; ++c) a[c] = sh[threadIdx.x * 8 + c];
        for (int g = 1; g < RPAR; ++g) {
            const float* p = &sh[(g * TPR + threadIdx.x) * 8];
#pragma unroll
            for (int c = 0; c < 8; ++c) a[c] += p[c];
        }
        float* dst = &PART[((size_t)b * SB + blockIdx.x) * (2 * O)];
#pragma unroll
        for (int c = 0; c < 4; ++c) { dst[o + c] = a[c]; dst[O + o + c] = a[4 + c]; }
    }
}

// ---------------------------------------------------------------- PART -> PART2
template<int O>
__global__ __launch_bounds__(256) void part_reduce_kernel(const float* __restrict__ PART,
                                                          float* __restrict__ PART2) {
    constexpr int ROWS = BATCH * SB;
    constexpr int RPG = ROWS / PR;
    int g = blockIdx.x;
    for (int col = threadIdx.x; col < 2 * O; col += 256) {
        float s = 0.f;
        for (int r = 0; r < RPG; ++r)
            s += PART[(size_t)(g * RPG + r) * (2 * O) + col];
        PART2[(size_t)g * (2 * O) + col] = s;
    }
}

template<int O>
__global__ void bnp_kernel(const float* __restrict__ PART2, const float* __restrict__ g,
                           const float* __restrict__ beta, float* __restrict__ bnp) {
    int o = threadIdx.x;
    float s = 0.f, ss = 0.f;
    for (int p = 0; p < PR; ++p) {
        s += PART2[(size_t)p * (2 * O) + o];
        ss += PART2[(size_t)p * (2 * O) + O + o];
    }
    const float cnt = (float)NROWS * (float)KNN;
    float m = s / cnt;
    float var = ss / cnt - m * m;
    float sc = g[o] / sqrtf(var + EPSV);
    bnp[o] = sc;
    bnp[O + o] = beta[o] - m * sc;
}

// ---------------------------------------------------------------- apply (stages 1..3)
template<int O>
__global__ __launch_bounds__(256) void applyb_kernel(const float* __restrict__ HMAX,
                                                     const float* __restrict__ HMIN,
                                                     const float* __restrict__ bnp,
                                                     float* __restrict__ Xn) {
    constexpr int TPR = O / 4;
    int e = blockIdx.x * 256 + threadIdx.x;
    int o = (e % TPR) * 4;
    size_t R = (size_t)(e / TPR) * O + o;
    const float4 hx = *(const float4*)&HMAX[R];
    const float4 hn = *(const float4*)&HMIN[R];
    float4 out;
    { float sc = bnp[o + 0], t = bnp[O + o + 0]; out.x = fmaxf(fmaf(sc, (sc >= 0.f) ? hx.x : hn.x, t), 0.f); }
    { float sc = bnp[o + 1], t = bnp[O + o + 1]; out.y = fmaxf(fmaf(sc, (sc >= 0.f) ? hx.y : hn.y, t), 0.f); }
    { float sc = bnp[o + 2], t = bnp[O + o + 2]; out.z = fmaxf(fmaf(sc, (sc >= 0.f) ? hx.z : hn.z, t), 0.f); }
    { float sc = bnp[o + 3], t = bnp[O + o + 3]; out.w = fmaxf(fmaf(sc, (sc >= 0.f) ? hx.w : hn.w, t), 0.f); }
    *(float4*)&Xn[R] = out;
}

// ---------------------------------------------------------------- stage-4 apply: dense -> point-max -> G0T
__global__ __launch_bounds__(256) void applyb4_kernel(const float* __restrict__ HMAX,
                                                      const float* __restrict__ HMIN,
                                                      const float* __restrict__ bnp,
                                                      float* __restrict__ g0T) {
    constexpr int O = 256;
    constexpr int TPR = O / 4;
    constexpr int RPAR = 256 / TPR;
    constexpr int AB = 32;
    constexpr int RPB = NPTS / AB;
    __shared__ float sh[256 * 4];
    int b = blockIdx.z;
    int otid = threadIdx.x & (TPR - 1);
    int o = otid * 4;
    int rsub = threadIdx.x >> 6;
    int rbase = blockIdx.x * RPB;
    float sc0 = bnp[o + 0], t0 = bnp[O + o + 0];
    float sc1 = bnp[o + 1], t1 = bnp[O + o + 1];
    float sc2 = bnp[o + 2], t2 = bnp[O + o + 2];
    float sc3 = bnp[o + 3], t3 = bnp[O + o + 3];
    float ym0 = 0.f, ym1 = 0.f, ym2 = 0.f, ym3 = 0.f;
    for (int r = rbase + rsub; r < rbase + RPB; r += RPAR) {
        size_t R = (size_t)(b * NPTS + r) * O + o;
        const float4 hx = *(const float4*)&HMAX[R];
        const float4 hn = *(const float4*)&HMIN[R];
        ym0 = fmaxf(ym0, fmaf(sc0, (sc0 >= 0.f) ? hx.x : hn.x, t0));
        ym1 = fmaxf(ym1, fmaf(sc1, (sc1 >= 0.f) ? hx.y : hn.y, t1));
        ym2 = fmaxf(ym2, fmaf(sc2, (sc2 >= 0.f) ? hx.z : hn.z, t2));
        ym3 = fmaxf(ym3, fmaf(sc3, (sc3 >= 0.f) ? hx.w : hn.w, t3));
    }
    float* my = &sh[threadIdx.x * 4];
    my[0] = ym0; my[1] = ym1; my[2] = ym2; my[3] = ym3;
    __syncthreads();
    if (threadIdx.x < TPR) {
        float a0 = ym0, a1 = ym1, a2 = ym2, a3 = ym3;
        for (int g = 1; g < RPAR; ++g) {
            const float* p = &sh[(g * TPR + threadIdx.x) * 4];
            a0 = fmaxf(a0, p[0]); a1 = fmaxf(a1, p[1]);
            a2 = fmaxf(a2, p[2]); a3 = fmaxf(a3, p[3]);
        }
        a0 = fmaxf(a0, 0.f); a1 = fmaxf(a1, 0.f);
        a2 = fmaxf(a2, 0.f); a3 = fmaxf(a3, 0.f);
        atomicMax((int*)&g0T[(o + 0) * 8 + b], __float_as_int(a0));
        atomicMax((int*)&g0T[(o + 1) * 8 + b], __float_as_int(a1));
        atomicMax((int*)&g0T[(o + 2) * 8 + b], __float_as_int(a2));
        atomicMax((int*)&g0T[(o + 3) * 8 + b], __float_as_int(a3));
    }
}

// ---------------------------------------------------------------- point-max of X2/X3 into G0T channels [256,448)
__global__ __launch_bounds__(256) void gmax23_kernel(const float* __restrict__ X2,
                                                     const float* __restrict__ X3,
                                                     float* __restrict__ g0T) {
    int b = blockIdx.x;
    int n0 = blockIdx.y * 32;
    int o = threadIdx.x;
    if (o >= 192) return;
    const float* src; int col, stride, ch;
    if (o < 128) { src = X3; col = o;       stride = 128; ch = 256 + o; }
    else         { src = X2; col = o - 128; stride = 64;  ch = 384 + (o - 128); }
    float m = 0.f;
#pragma unroll 8
    for (int n = n0; n < n0 + 32; ++n)
        m = fmaxf(m, src[((size_t)(b * NPTS + n)) * stride + col]);
    atomicMax((int*)&g0T[ch * 8 + b], __float_as_int(m));
}

// ---------------------------------------------------------------- fc weight transpose
__global__ __launch_bounds__(256) void transpose_kernel(const float* __restrict__ w,
                                                        float* __restrict__ wT, int O, int Cc) {
    int e = blockIdx.x * 256 + threadIdx.x;
    if (e >= O * Cc) return;
    int o = e / Cc, c = e - o * Cc;
    wT[c * O + o] = w[e];
}

// ---------------------------------------------------------------- fc1 + bnf1 + relu
__global__ __launch_bounds__(64) void fc1_kernel(const float* __restrict__ g0T,
                                                 const float* __restrict__ w1T,
                                                 const float* __restrict__ b1,
                                                 const float* __restrict__ bng,
                                                 const float* __restrict__ bnb,
                                                 float* __restrict__ A) {
    int o = blockIdx.x * 64 + threadIdx.x;
    float acc[8] = {};
    for (int c = 0; c < 448; ++c) {
        float wv = w1T[c * 256 + o];
        const float4 h0 = *(const float4*)&g0T[c * 8];
        const float4 h1 = *(const float4*)&g0T[c * 8 + 4];
        acc[0] = fmaf(wv, h0.x, acc[0]); acc[1] = fmaf(wv, h0.y, acc[1]);
        acc[2] = fmaf(wv, h0.z, acc[2]); acc[3] = fmaf(wv, h0.w, acc[3]);
        acc[4] = fmaf(wv, h1.x, acc[4]); acc[5] = fmaf(wv, h1.y, acc[5]);
        acc[6] = fmaf(wv, h1.z, acc[6]); acc[7] = fmaf(wv, h1.w, acc[7]);
    }
    float bb = b1[o];
    float h[8], m = 0.f;
#pragma unroll
    for (int b = 0; b < 8; ++b) { h[b] = acc[b] + bb; m += h[b]; }
    m *= 0.125f;
    float var = 0.f;
#pragma unroll
    for (int b = 0; b < 8; ++b) { float d = h[b] - m; var = fmaf(d, d, var); }
    var *= 0.125f;
    float sc = bng[o] / sqrtf(var + EPSV);
    float t = bnb[o] - m * sc;
#pragma unroll
    for (int b = 0; b < 8; ++b) A[o * 8 + b] = fmaxf(fmaf(sc, h[b], t), 0.f);
}

// ---------------------------------------------------------------- fc2..fc4 tail (one block)
__global__ __launch_bounds__(256) void tail_kernel(const float* __restrict__ A,
                                                   const float* __restrict__ w2T, const float* __restrict__ b2,
                                                   const float* __restrict__ g2, const float* __restrict__ be2,
                                                   const float* __restrict__ w3T, const float* __restrict__ b3,
                                                   const float* __restrict__ g3, const float* __restrict__ be3,
                                                   const float* __restrict__ w4, const float* __restrict__ b4,
                                                   float* __restrict__ out) {
    __shared__ __align__(16) float B2[128 * 8];
    __shared__ __align__(16) float C3[16 * 8];
    int tid = threadIdx.x;
    if (tid < 128) {
        int o = tid;
        float acc[8] = {};
        for (int c = 0; c < 256; ++c) {
            float wv = w2T[c * 128 + o];
            const float4 a0 = *(const float4*)&A[c * 8];
            const float4 a1 = *(const float4*)&A[c * 8 + 4];
            acc[0] = fmaf(wv, a0.x, acc[0]); acc[1] = fmaf(wv, a0.y, acc[1]);
            acc[2] = fmaf(wv, a0.z, acc[2]); acc[3] = fmaf(wv, a0.w, acc[3]);
            acc[4] = fmaf(wv, a1.x, acc[4]); acc[5] = fmaf(wv, a1.y, acc[5]);
            acc[6] = fmaf(wv, a1.z, acc[6]); acc[7] = fmaf(wv, a1.w, acc[7]);
        }
        float bb = b2[o];
        float h[8], m = 0.f;
#pragma unroll
        for (int b = 0; b < 8; ++b) { h[b] = acc[b] + bb; m += h[b]; }
        m *= 0.125f;
        float var = 0.f;
#pragma unroll
        for (int b = 0; b < 8; ++b) { float d = h[b] - m; var = fmaf(d, d, var); }
        var *= 0.125f;
        float sc = g2[o] / sqrtf(var + EPSV);
        float t = be2[o] - m * sc;
#pragma unroll
        for (int b = 0; b < 8; ++b) B2[o * 8 + b] = fmaxf(fmaf(sc, h[b], t), 0.f);
    }
    __syncthreads();
    if (tid < 16) {
        int o = tid;
        float acc[8] = {};
        for (int c = 0; c < 128; ++c) {
            float wv = w3T[c * 16 + o];
            const float4 a0 = *(const float4*)&B2[c * 8];
            const float4 a1 = *(const float4*)&B2[c * 8 + 4];
            acc[0] = fmaf(wv, a0.x, acc[0]); acc[1] = fmaf(wv, a0.y, acc[1]);
            acc[2] = fmaf(wv, a0.z, acc[2]); acc[3] = fmaf(wv, a0.w, acc[3]);
            acc[4] = fmaf(wv, a1.x, acc[4]); acc[5] = fmaf(wv, a1.y, acc[5]);
            acc[6] = fmaf(wv, a1.z, acc[6]); acc[7] = fmaf(wv, a1.w, acc[7]);
        }
        float bb = b3[o];
        float h[8], m = 0.f;
#pragma unroll
        for (int b = 0; b < 8; ++b) { h[b] = acc[b] + bb; m += h[b]; }
        m *= 0.125f;
        float var = 0.f;
#pragma unroll
        for (int b = 0; b < 8; ++b) { float d = h[b] - m; var = fmaf(d, d, var); }
        var *= 0.125f;
        float sc = g3[o] / sqrtf(var + EPSV);
        float t = be3[o] - m * sc;
#pragma unroll
        for (int b = 0; b < 8; ++b) C3[o * 8 + b] = fmaxf(fmaf(sc, h[b], t), 0.f);
    }
    __syncthreads();
    if (tid < 8) {
        int b = tid;
        float acc = b4[0];
#pragma unroll
        for (int c = 0; c < 16; ++c) acc = fmaf(w4[c], C3[c * 8 + b], acc);
        out[b] = acc;
    }
}

// ================================================================ host side
struct Arena {
    char* base; size_t off, cap; bool ok;
    Arena(void* b, size_t c) : base((char*)b), off(0), cap(c), ok(true) {}
    void* get(size_t bytes) {
        char* p = base + off;
        off += (bytes + 255) & ~(size_t)255;
        if (off > cap) ok = false;
        return p;
    }
};

// one EdgeConv stage, output stored to Xout (stages 1..3)
template<int C, int O>
static void run_stage(const float* Xin, float* Xout, const float* W, const float* bias,
                      const float* g, const float* be, float* SCRBIG, float* UVA,
                      u16* XPH, u16* XPL, u16* WPH, u16* WPL,
                      u16* IDX, float* SQ, float* PART, float* PART2, float* BNP, hipStream_t s) {
    dim3 blk(256);
    float* HMAX = SCRBIG;
    float* HMIN = SCRBIG + (size_t)NROWS * O;
    u64* CANDB = (u64*)SCRBIG;                   // alias: dead until statsb writes HMAX/HMIN
    sqnorm_kernel<C><<<NROWS / 256, blk, 0, s>>>(Xin, SQ);
    if constexpr (C >= 32) {
        split_pack_kernel<C><<<NROWS * C / 8 / 256, blk, 0, s>>>(Xin, XPH, XPL);
        knn_kernel<C><<<dim3(NCH, NPTS / 16, BATCH), blk, 0, s>>>(XPH, XPL, SQ, CANDB);
        knn_merge_kernel<<<dim3(NPTS / 4, 1, BATCH), blk, 0, s>>>(CANDB, IDX);
        wsplit_pack_kernel<C, O><<<(2 * O * C / 8 + 255) / 256, blk, 0, s>>>(W, WPH, WPL);
        uvb_mfma_kernel<C, O><<<dim3(2 * O / 64, NPTS / 64, BATCH), blk, 0, s>>>(XPH, XPL, WPH, WPL, bias, UVA);
    } else {
        // stage 1: EXACT f32 distances (3-D near-ties are below split-bf16 error)
        for (int b0 = 0; b0 < BATCH; b0 += 4) {
            dist_gemm_kernel<C><<<dim3(NPTS / 64, NPTS / 64, 4), blk, 0, s>>>(Xin, SCRBIG, b0);
            topk_kernel<<<dim3(NPTS / 4, 1, 4), blk, 0, s>>>(SCRBIG, SQ, IDX, b0);
        }
        uvb_gemm_kernel<C, O><<<dim3(2 * O / 64, NPTS / 64, BATCH), blk, 0, s>>>(Xin, W, bias, UVA);
    }
    statsb_kernel<O><<<dim3(SB, 1, BATCH), blk, 0, s>>>(UVA, IDX, PART, HMAX, HMIN);
    part_reduce_kernel<O><<<PR, blk, 0, s>>>(PART, PART2);
    bnp_kernel<O><<<1, O, 0, s>>>(PART2, g, be, BNP);
    applyb_kernel<O><<<NROWS * (O / 4) / 256, blk, 0, s>>>(HMAX, HMIN, BNP, Xout);
}

// stage 4
static void run_stage4(const float* Xin, const float* W, const float* bias,
                       const float* g, const float* be, float* SCRBIG, float* UVA,
                       u16* XPH, u16* XPL, u16* WPH, u16* WPL,
                       u16* IDX, float* SQ, float* PART, float* PART2, float* BNP, float* G0T,
                       hipStream_t s) {
    constexpr int C = 128;
    dim3 blk(256);
    float* HMAX = SCRBIG;
    float* HMIN = SCRBIG + (size_t)NROWS * 256;
    u64* CANDB = (u64*)SCRBIG;
    sqnorm_kernel<C><<<NROWS / 256, blk, 0, s>>>(Xin, SQ);
    split_pack_kernel<C><<<NROWS * C / 8 / 256, blk, 0, s>>>(Xin, XPH, XPL);
    knn_kernel<C><<<dim3(NCH, NPTS / 16, BATCH), blk, 0, s>>>(XPH, XPL, SQ, CANDB);
    knn_merge_kernel<<<dim3(NPTS / 4, 1, BATCH), blk, 0, s>>>(CANDB, IDX);
    wsplit_pack_kernel<C, 256><<<(512 * C / 8 + 255) / 256, blk, 0, s>>>(W, WPH, WPL);
    uvb_mfma_kernel<C, 256><<<dim3(8, NPTS / 64, BATCH), blk, 0, s>>>(XPH, XPL, WPH, WPL, bias, UVA);
    statsb_kernel<256><<<dim3(SB, 1, BATCH), blk, 0, s>>>(UVA, IDX, PART, HMAX, HMIN);
    part_reduce_kernel<256><<<PR, blk, 0, s>>>(PART, PART2);
    bnp_kernel<256><<<1, 256, 0, s>>>(PART2, g, be, BNP);
    fill_zero_kernel<<<14, blk, 0, s>>>(G0T, 448 * 8);
    applyb4_kernel<<<dim3(32, 1, BATCH), blk, 0, s>>>(HMAX, HMIN, BNP, G0T);
}

extern "C" void kernel_launch(void* const* d_in, const int* in_sizes, int n_in,
                              void* d_out, int out_size, void* d_ws, size_t ws_size,
                              hipStream_t stream) {
    float* out = (float*)d_out;
    if (n_in < 31) { diag_kernel<<<1, 64, 0, stream>>>(out, 9000.f); return; }

    const float* x       = (const float*)d_in[0];
    const float* cw[4]   = {(const float*)d_in[1], (const float*)d_in[5], (const float*)d_in[9],  (const float*)d_in[13]};
    const float* cb[4]   = {(const float*)d_in[2], (const float*)d_in[6], (const float*)d_in[10], (const float*)d_in[14]};
    const float* bg[4]   = {(const float*)d_in[3], (const float*)d_in[7], (const float*)d_in[11], (const float*)d_in[15]};
    const float* bb[4]   = {(const float*)d_in[4], (const float*)d_in[8], (const float*)d_in[12], (const float*)d_in[16]};
    const float* fc1_w = (const float*)d_in[17]; const float* fc1_b = (const float*)d_in[18];
    const float* bnf1_g = (const float*)d_in[19]; const float* bnf1_b = (const float*)d_in[20];
    const float* fc2_w = (const float*)d_in[21]; const float* fc2_b = (const float*)d_in[22];
    const float* bnf2_g = (const float*)d_in[23]; const float* bnf2_b = (const float*)d_in[24];
    const float* fc3_w = (const float*)d_in[25]; const float* fc3_b = (const float*)d_in[26];
    const float* bnf3_g = (const float*)d_in[27]; const float* bnf3_b = (const float*)d_in[28];
    const float* fc4_w = (const float*)d_in[29]; const float* fc4_b = (const float*)d_in[30];

    Arena ar(d_ws, ws_size);
    float* X1 = (float*)ar.get((size_t)NROWS * 64 * 4);
    float* X2 = (float*)ar.get((size_t)NROWS * 64 * 4);
    float* X3 = (float*)ar.get((size_t)NROWS * 128 * 4);
    u16* IDX = (u16*)ar.get((size_t)NROWS * KNN * 2);
    float* SQ = (float*)ar.get((size_t)NROWS * 4);
    float* PART = (float*)ar.get((size_t)BATCH * SB * 512 * 4);
    float* PART2 = (float*)ar.get((size_t)PR * 512 * 4);
    float* BNP = (float*)ar.get(512 * 4);
    float* G0T = (float*)ar.get(448 * 8 * 4);
    float* ABUF = (float*)ar.get(256 * 8 * 4);
    u16* XPH = (u16*)ar.get((size_t)NROWS * 128 * 2);
    u16* XPL = (u16*)ar.get((size_t)NROWS * 128 * 2);
    u16* WPH = (u16*)ar.get(512 * 128 * 2);
    u16* WPL = (u16*)ar.get(512 * 128 * 2);
    float* SCRBIG = (float*)ar.get((size_t)4 * NPTS * NPTS * 4);  // stage1 DIST x4 / CAND / HMAX+HMIN+UVA / W-transposes
    if (!ar.ok) {
        diag_kernel<<<1, 64, 0, stream>>>(out, 3000.f + (float)(ws_size >> 20));
        return;
    }
    float* UVA = SCRBIG + (size_t)2 * NPTS * NPTS;

    dim3 blk(256);
    run_stage<3, 64>(x, X1, cw[0], cb[0], bg[0], bb[0], SCRBIG, UVA, XPH, XPL, WPH, WPL, IDX, SQ, PART, PART2, BNP, stream);
    run_stage<64, 64>(X1, X2, cw[1], cb[1], bg[1], bb[1], SCRBIG, UVA, XPH, XPL, WPH, WPL, IDX, SQ, PART, PART2, BNP, stream);
    run_stage<64, 128>(X2, X3, cw[2], cb[2], bg[2], bb[2], SCRBIG, UVA, XPH, XPL, WPH, WPL, IDX, SQ, PART, PART2, BNP, stream);
    run_stage4(X3, cw[3], cb[3], bg[3], bb[3], SCRBIG, UVA, XPH, XPL, WPH, WPL, IDX, SQ, PART, PART2, BNP, G0T, stream);

    gmax23_kernel<<<dim3(BATCH, 64), blk, 0, stream>>>(X2, X3, G0T);

    float* W1T = SCRBIG;
    float* W2T = W1T + 448 * 256;
    float* W3T = W2T + 256 * 128;
    transpose_kernel<<<(256 * 448 + 255) / 256, blk, 0, stream>>>(fc1_w, W1T, 256, 448);
    transpose_kernel<<<(128 * 256 + 255) / 256, blk, 0, stream>>>(fc2_w, W2T, 128, 256);
    transpose_kernel<<<(16 * 128 + 255) / 256, blk, 0, stream>>>(fc3_w, W3T, 16, 128);
    fc1_kernel<<<4, 64, 0, stream>>>(G0T, W1T, fc1_b, bnf1_g, bnf1_b, ABUF);
    tail_kernel<<<1, 256, 0, stream>>>(ABUF, W2T, fc2_b, bnf2_g, bnf2_b,
                                       W3T, fc3_b, bnf3_g, bnf3_b, fc4_w, fc4_b, out);
}

// Round 17
// 660.372 us; speedup vs baseline: 1.3157x; 1.0876x over previous
//
#include <hip/hip_runtime.h>
#include <hip/hip_bf16.h>
#include <cfloat>

constexpr int BATCH = 8, NPTS = 2048, KNN = 20;
constexpr int NROWS = BATCH * NPTS;
constexpr float EPSV = 1e-5f;
constexpr int SB = 256;                          // statsb blocks per batch
constexpr int PR = 64;                           // reduced partials
constexpr int RBB = NPTS / 16;                   // row-blocks per batch (128)
constexpr int KC2 = 48;                          // knn per-row candidate cap (per 512-col chunk)
constexpr int NCH = 4;                           // knn col chunks (512 cols each)

using u16 = unsigned short;
using u64 = unsigned long long;
typedef __attribute__((ext_vector_type(8))) short short8;
typedef __attribute__((ext_vector_type(4))) float f32x4;

// ---------------------------------------------------------------- diag / fill
__global__ void diag_kernel(float* out, float v) {
    if (threadIdx.x < 8) out[threadIdx.x] = v;
}

__global__ __launch_bounds__(256) void fill_zero_kernel(float* __restrict__ p, int n) {
    int i = blockIdx.x * 256 + threadIdx.x;
    if (i < n) p[i] = 0.f;
}

// ---------------------------------------------------------------- sqnorm over all rows
template<int C>
__global__ __launch_bounds__(256) void sqnorm_kernel(const float* __restrict__ X,
                                                     float* __restrict__ sq) {
    int r = blockIdx.x * 256 + threadIdx.x;
    const float* x = X + (size_t)r * C;
    float s = 0.f;
#pragma unroll
    for (int c = 0; c < C; ++c) { float v = x[c]; s = fmaf(v, v, s); }
    sq[r] = s;
}

// ---------------------------------------------------------------- split X -> hi/lo bf16 in PACKED MFMA-fragment layout
template<int C>
__global__ __launch_bounds__(256) void split_pack_kernel(const float* __restrict__ X,
                                                         u16* __restrict__ XPH,
                                                         u16* __restrict__ XPL) {
    constexpr int KB = C / 32;
    int e = blockIdx.x * 256 + threadIdx.x;     // one short8 fragment per thread
    int lane = e & 63;
    int rest = e >> 6;
    int kb = rest % KB;
    int Rb = rest / KB;
    int row = Rb * 16 + (lane & 15);
    int col = kb * 32 + (lane >> 4) * 8;
    const float* src = &X[(size_t)row * C + col];
    u16 h[8], l[8];
#pragma unroll
    for (int q = 0; q < 8; ++q) {
        float v = src[q];
        __hip_bfloat16 hb = __float2bfloat16(v);
        float hf = __bfloat162float(hb);
        __hip_bfloat16 lb = __float2bfloat16(v - hf);
        h[q] = *(u16*)&hb; l[q] = *(u16*)&lb;
    }
    u16* dh = &XPH[(size_t)e * 8];
    u16* dl = &XPL[(size_t)e * 8];
#pragma unroll
    for (int q = 0; q < 8; ++q) { dh[q] = h[q]; dl[q] = l[q]; }
}

// ---------------------------------------------------------------- split W -> packed hi/lo (n<O: W1; n>=O: W2-W1)
template<int C, int O>
__global__ __launch_bounds__(256) void wsplit_pack_kernel(const float* __restrict__ W,
                                                          u16* __restrict__ WPH,
                                                          u16* __restrict__ WPL) {
    constexpr int KB = C / 32;
    constexpr int NFRAG = (2 * O / 16) * KB * 64;
    int e = blockIdx.x * 256 + threadIdx.x;
    if (e >= NFRAG) return;
    int lane = e & 63;
    int rest = e >> 6;
    int kb = rest % KB;
    int Nb = rest / KB;
    int n = Nb * 16 + (lane & 15);
    int col = kb * 32 + (lane >> 4) * 8;
    u16 h[8], l[8];
#pragma unroll
    for (int q = 0; q < 8; ++q) {
        int c = col + q;
        float wv = (n < O) ? W[(size_t)n * (2 * C) + c]
                           : W[(size_t)(n - O) * (2 * C) + C + c] - W[(size_t)(n - O) * (2 * C) + c];
        __hip_bfloat16 hb = __float2bfloat16(wv);
        float hf = __bfloat162float(hb);
        __hip_bfloat16 lb = __float2bfloat16(wv - hf);
        h[q] = *(u16*)&hb; l[q] = *(u16*)&lb;
    }
    u16* dh = &WPH[(size_t)e * 8];
    u16* dl = &WPL[(size_t)e * 8];
#pragma unroll
    for (int q = 0; q < 8; ++q) { dh[q] = h[q]; dl[q] = l[q]; }
}

// ---------------------------------------------------------------- wave-64 bitonic sorts
__device__ __forceinline__ float bitonic64_desc_f32(float key, int lane) {
#pragma unroll
    for (int k = 2; k <= 64; k <<= 1) {
#pragma unroll
        for (int j = k >> 1; j > 0; j >>= 1) {
            float p = __shfl_xor(key, j);
            bool keepMax = (((lane & j) == 0) == ((lane & k) == 0));
            key = ((key > p) == keepMax) ? key : p;
        }
    }
    return key;
}

__device__ __forceinline__ u64 bitonic64_desc_u64(u64 key, int lane) {
#pragma unroll
    for (int k = 2; k <= 64; k <<= 1) {
#pragma unroll
        for (int j = k >> 1; j > 0; j >>= 1) {
            u64 p = __shfl_xor(key, j);
            bool keepMax = (((lane & j) == 0) == ((lane & k) == 0));
            key = ((key > p) == keepMax) ? key : p;
        }
    }
    return key;
}

// ---------------------------------------------------------------- stage-1 fused dist+topk (C=3, exact f32, LDS-resident points)
// dot and sq use the SAME fmaf chains as the old dist_gemm/sqnorm -> bit-identical values.
__global__ __launch_bounds__(256) void topk1_kernel(const float* __restrict__ X,
                                                    u16* __restrict__ idx_out) {
    constexpr int Q1 = 64;
    __shared__ float px[NPTS], py[NPTS], pz[NPTS], sqs[NPTS];
    __shared__ u64 qkey[4][Q1];
    __shared__ int qn[4];
    int b = blockIdx.z;
    const float* Xb = X + (size_t)b * NPTS * 3;
    for (int k = threadIdx.x; k < NPTS; k += 256) {
        float xx = Xb[k * 3 + 0], yy = Xb[k * 3 + 1], zz = Xb[k * 3 + 2];
        px[k] = xx; py[k] = yy; pz[k] = zz;
        float s = fmaf(xx, xx, 0.f); s = fmaf(yy, yy, s); s = fmaf(zz, zz, s);
        sqs[k] = s;
    }
    int w = threadIdx.x >> 6, lane = threadIdx.x & 63;
    if (lane == 0) qn[w] = 0;
    __syncthreads();
    int i = blockIdx.x * 4 + w;
    float xi = px[i], yi = py[i], zi = pz[i], sqi = sqs[i];
    float vals[32];
    float mx = -FLT_MAX;
#pragma unroll
    for (int t = 0; t < 32; ++t) {
        int j = lane + 64 * t;
        float d = fmaf(xi, px[j], 0.f);
        d = fmaf(yi, py[j], d);
        d = fmaf(zi, pz[j], d);
        float v = (2.f * d - sqi - sqs[j]) + 0.f;
        vals[t] = v;
        mx = fmaxf(mx, v);
    }
    float sm = bitonic64_desc_f32(mx, lane);
    float T0 = __shfl(sm, 19);                   // 20th lane-max <= true v20
#pragma unroll
    for (int t = 0; t < 32; ++t) {
        float v = vals[t];
        if (v >= T0) {
            unsigned j = (unsigned)(lane + 64 * t);
            unsigned bu = __float_as_uint(v);
            unsigned u = (bu & 0x80000000u) ? ~bu : (bu | 0x80000000u);
            u64 key = ((u64)u << 32) | (u64)(0xFFFFFFFFu - j);
            int slot = atomicAdd(&qn[w], 1);
            if (slot < Q1) qkey[w][slot] = key;
        }
    }
    int Cn = qn[w]; if (Cn > Q1) Cn = Q1;
    u64 key = (lane < Cn) ? qkey[w][lane] : 0ull;
    key = bitonic64_desc_u64(key, lane);
    if (lane < 20) {
        unsigned j = 0xFFFFFFFFu - (unsigned)(key & 0xFFFFFFFFull);
        idx_out[((size_t)(b * NPTS + i)) * KNN + lane] = (u16)j;
    }
}

// ---------------------------------------------------------------- fused kNN (stages 2..4): MFMA -> LDS D; ballot-compact survivors (no sort)
template<int C>
__global__ __launch_bounds__(256) void knn_kernel(const u16* __restrict__ XPH,
                                                  const u16* __restrict__ XPL,
                                                  const float* __restrict__ SQ,
                                                  u64* __restrict__ CAND,
                                                  int* __restrict__ CNTS) {
    constexpr int KB = C / 32;
    __shared__ float Dl[16][516];
    int b = blockIdx.z;
    int chunk = blockIdx.x;                      // 0..3 (512 cols each)
    int i0 = blockIdx.y * 16;                    // grid.y = 128
    int w = threadIdx.x >> 6, lane = threadIdx.x & 63;
    int l15 = lane & 15, g = lane >> 4;
    size_t base = (size_t)b * RBB * KB * 512;
    const float* sqb = SQ + b * NPTS;

    int Rba = i0 / 16;
    short8 ahi[KB], alo[KB];
#pragma unroll
    for (int kb = 0; kb < KB; ++kb) {
        size_t ia = base + ((size_t)(Rba * KB + kb) * 64 + lane) * 8;
        ahi[kb] = *(const short8*)&XPH[ia];
        alo[kb] = *(const short8*)&XPL[ia];
    }
    float sqr[4];
#pragma unroll
    for (int r = 0; r < 4; ++r) sqr[r] = sqb[i0 + g * 4 + r];

    // MFMA phase: 32 col-blocks; wave w handles c = w + 4t
#pragma unroll
    for (int t = 0; t < 8; ++t) {
        int c = w + 4 * t;
        int Cb = chunk * 32 + c;
        f32x4 acc = {0.f, 0.f, 0.f, 0.f};
#pragma unroll
        for (int kb = 0; kb < KB; ++kb) {
            size_t ib = base + ((size_t)(Cb * KB + kb) * 64 + lane) * 8;
            short8 bhi = *(const short8*)&XPH[ib];
            short8 blo = *(const short8*)&XPL[ib];
            acc = __builtin_amdgcn_mfma_f32_16x16x32_bf16(ahi[kb], bhi, acc, 0, 0, 0);
            acc = __builtin_amdgcn_mfma_f32_16x16x32_bf16(ahi[kb], blo, acc, 0, 0, 0);
            acc = __builtin_amdgcn_mfma_f32_16x16x32_bf16(alo[kb], bhi, acc, 0, 0, 0);
        }
        int colg = Cb * 16 + l15;
        float sqc = sqb[colg];
        int cl = c * 16 + l15;
#pragma unroll
        for (int r = 0; r < 4; ++r)
            Dl[g * 4 + r][cl] = (2.f * acc[r] - sqr[r] - sqc) + 0.f;
    }
    __syncthreads();

    // selection: wave w owns rows w*4 .. w*4+3; ballot compaction, NO per-chunk sort
    for (int rr = 0; rr < 4; ++rr) {
        int row = w * 4 + rr;
        float vv[8];
        float mx = -FLT_MAX;
#pragma unroll
        for (int q = 0; q < 8; ++q) {
            vv[q] = Dl[row][lane + 64 * q];
            mx = fmaxf(mx, vv[q]);
        }
        float sv = bitonic64_desc_f32(mx, lane);
        float T = __shfl(sv, 19);                // 20th lane-max <= true v20 (>=20 survivors)
        size_t cb = ((size_t)(b * NPTS + i0 + row) * NCH + chunk) * KC2;
        int cbase = 0;
#pragma unroll
        for (int q = 0; q < 8; ++q) {
            bool p = vv[q] >= T;
            u64 mask = __ballot(p);
            int ofs = __popcll(mask & ((1ull << lane) - 1ull));
            if (p) {
                int slot = cbase + ofs;
                if (slot < KC2) {
                    unsigned colg = (unsigned)(chunk * 512 + lane + 64 * q);
                    unsigned bu = __float_as_uint(vv[q]);
                    unsigned u = (bu & 0x80000000u) ? ~bu : (bu | 0x80000000u);
                    CAND[cb + slot] = ((u64)u << 32) | (u64)(0xFFFFFFFFu - colg);
                }
            }
            cbase += __popcll(mask);
        }
        if (lane == 0)
            CNTS[(size_t)(b * NPTS + i0 + row) * NCH + chunk] = (cbase < KC2) ? cbase : KC2;
    }
}

// ---------------------------------------------------------------- merge unsorted chunk candidates -> exact top-20 (one wave per row)
__global__ __launch_bounds__(256) void knn_merge_kernel(const u64* __restrict__ CAND,
                                                        const int* __restrict__ CNTS,
                                                        u16* __restrict__ idx_out) {
    int b = blockIdx.z;
    int w = threadIdx.x >> 6, lane = threadIdx.x & 63;
    int i = blockIdx.x * 4 + w;
    size_t rbase = (size_t)(b * NPTS + i) * NCH;
    int c0 = CNTS[rbase + 0];
    u64 key = (lane < c0) ? CAND[(rbase + 0) * KC2 + lane] : 0ull;
    key = bitonic64_desc_u64(key, lane);
    for (int ch = 1; ch < NCH; ++ch) {
        int cn = CNTS[rbase + ch];
        int off = 0;
        while (off < cn) {                       // wave-uniform loop
            int take = cn - off; if (take > 44) take = 44;
            if (lane >= 20) {
                int s2 = lane - 20;
                key = (s2 < take) ? CAND[(rbase + ch) * KC2 + off + s2] : 0ull;
            }
            key = bitonic64_desc_u64(key, lane);
            off += take;
        }
    }
    if (lane < 20) {
        unsigned j = 0xFFFFFFFFu - (unsigned)(key & 0xFFFFFFFFull);
        idx_out[(size_t)(b * NPTS + i) * KNN + lane] = (u16)j;
    }
}

// ---------------------------------------------------------------- uvb via MFMA from packed fragments
template<int C, int O>
__global__ __launch_bounds__(256) void uvb_mfma_kernel(const u16* __restrict__ XPH,
                                                       const u16* __restrict__ XPL,
                                                       const u16* __restrict__ WPH,
                                                       const u16* __restrict__ WPL,
                                                       const float* __restrict__ bias,
                                                       float* __restrict__ UVA) {
    constexpr int KB = C / 32;
    int b = blockIdx.z;
    int r0 = blockIdx.y * 64, n0 = blockIdx.x * 64;
    int w = threadIdx.x >> 6, lane = threadIdx.x & 63;
    int l15 = lane & 15, g = lane >> 4;
    size_t base = (size_t)b * RBB * KB * 512;
    int Rba = r0 / 16 + w;
    short8 ahi[KB], alo[KB];
#pragma unroll
    for (int kb = 0; kb < KB; ++kb) {
        size_t ia = base + ((size_t)(Rba * KB + kb) * 64 + lane) * 8;
        ahi[kb] = *(const short8*)&XPH[ia];
        alo[kb] = *(const short8*)&XPL[ia];
    }
    float* UVb = UVA + (size_t)b * NPTS * 2 * O;
#pragma unroll
    for (int nt = 0; nt < 4; ++nt) {
        int Nb = n0 / 16 + nt;
        f32x4 acc = {0.f, 0.f, 0.f, 0.f};
#pragma unroll
        for (int kb = 0; kb < KB; ++kb) {
            size_t ib = ((size_t)(Nb * KB + kb) * 64 + lane) * 8;
            short8 bhi = *(const short8*)&WPH[ib];
            short8 blo = *(const short8*)&WPL[ib];
            acc = __builtin_amdgcn_mfma_f32_16x16x32_bf16(ahi[kb], bhi, acc, 0, 0, 0);
            acc = __builtin_amdgcn_mfma_f32_16x16x32_bf16(ahi[kb], blo, acc, 0, 0, 0);
            acc = __builtin_amdgcn_mfma_f32_16x16x32_bf16(alo[kb], bhi, acc, 0, 0, 0);
        }
        int n = n0 + nt * 16 + l15;
        float badd = (n >= O) ? bias[n - O] : 0.f;
        int rbase = r0 + w * 16 + g * 4;
#pragma unroll
        for (int r = 0; r < 4; ++r)
            UVb[(size_t)(rbase + r) * (2 * O) + n] = acc[r] + badd;
    }
}

// ---------------------------------------------------------------- f32 uvb (stage 1, C=3)
template<int C, int O>
__global__ __launch_bounds__(256) void uvb_gemm_kernel(const float* __restrict__ X,
                                                       const float* __restrict__ W,
                                                       const float* __restrict__ bias,
                                                       float* __restrict__ UVA) {
    constexpr int KC = (C < 32) ? C : 32;
    __shared__ __align__(16) float As[KC][68];
    __shared__ __align__(16) float Bs[KC][68];
    int b = blockIdx.z;
    int r0 = blockIdx.y * 64, n0 = blockIdx.x * 64;
    int tx = threadIdx.x & 15, ty = threadIdx.x >> 4;
    float acc[4][4] = {};
    for (int c0 = 0; c0 < C; c0 += KC) {
        for (int t = threadIdx.x; t < 64 * KC; t += 256) {
            int i = t / KC, c = t % KC;
            As[c][i] = X[(size_t)(b * NPTS + r0 + i) * C + c0 + c];
            int n = n0 + i;
            float wv;
            if (n < O) wv = W[(size_t)n * (2 * C) + c0 + c];
            else {
                int o = n - O;
                wv = W[(size_t)o * (2 * C) + C + c0 + c] - W[(size_t)o * (2 * C) + c0 + c];
            }
            Bs[c][i] = wv;
        }
        __syncthreads();
#pragma unroll
        for (int c = 0; c < KC; ++c) {
            const float4 av = *(const float4*)&As[c][ty * 4];
            const float4 bv = *(const float4*)&Bs[c][tx * 4];
            float ar[4] = {av.x, av.y, av.z, av.w};
            float br[4] = {bv.x, bv.y, bv.z, bv.w};
#pragma unroll
            for (int r = 0; r < 4; ++r)
#pragma unroll
                for (int q = 0; q < 4; ++q) acc[r][q] = fmaf(ar[r], br[q], acc[r][q]);
        }
        __syncthreads();
    }
    float badd[4] = {0.f, 0.f, 0.f, 0.f};
    if (n0 >= O) {
#pragma unroll
        for (int q = 0; q < 4; ++q) badd[q] = bias[n0 - O + tx * 4 + q];
    }
    float* UVb = UVA + (size_t)b * NPTS * 2 * O;
#pragma unroll
    for (int r = 0; r < 4; ++r) {
        float4 o4 = make_float4(acc[r][0] + badd[0], acc[r][1] + badd[1],
                                acc[r][2] + badd[2], acc[r][3] + badd[3]);
        *(float4*)&UVb[(size_t)(r0 + ty * 4 + r) * (2 * O) + n0 + tx * 4] = o4;
    }
}

// ---------------------------------------------------------------- stats: ONE gather pass -> block partials + dense HMAX/HMIN
template<int O>
__global__ __launch_bounds__(256) void statsb_kernel(const float* __restrict__ UVA,
                                                     const u16* __restrict__ idx,
                                                     float* __restrict__ PART,
                                                     float* __restrict__ HMAX,
                                                     float* __restrict__ HMIN) {
    constexpr int TPR = O / 4;
    constexpr int RPAR = 256 / TPR;
    constexpr int RPB = NPTS / SB;
    __shared__ float sh[256 * 8];
    int b = blockIdx.z;
    const float* UVb = UVA + (size_t)b * NPTS * 2 * O;
    int otid = threadIdx.x % TPR;
    int o = otid * 4;
    int rsub = threadIdx.x / TPR;
    int rbase = blockIdx.x * RPB;
    float s0 = 0, s1 = 0, s2 = 0, s3 = 0, q0 = 0, q1 = 0, q2 = 0, q3 = 0;
    for (int r = rbase + rsub; r < rbase + RPB; r += RPAR) {
        const float4 v4 = *(const float4*)&UVb[(size_t)r * (2 * O) + O + o];
        const u16* ix = idx + (size_t)(b * NPTS + r) * KNN;
        float mx0 = -FLT_MAX, mx1 = -FLT_MAX, mx2 = -FLT_MAX, mx3 = -FLT_MAX;
        float mn0 = FLT_MAX, mn1 = FLT_MAX, mn2 = FLT_MAX, mn3 = FLT_MAX;
#pragma unroll
        for (int k = 0; k < KNN; ++k) {
            int j = (int)ix[k] & (NPTS - 1);
            const float4 u4 = *(const float4*)&UVb[(size_t)j * (2 * O) + o];
            float h0 = u4.x + v4.x, h1 = u4.y + v4.y, h2 = u4.z + v4.z, h3 = u4.w + v4.w;
            s0 += h0; q0 = fmaf(h0, h0, q0); mx0 = fmaxf(mx0, h0); mn0 = fminf(mn0, h0);
            s1 += h1; q1 = fmaf(h1, h1, q1); mx1 = fmaxf(mx1, h1); mn1 = fminf(mn1, h1);
            s2 += h2; q2 = fmaf(h2, h2, q2); mx2 = fmaxf(mx2, h2); mn2 = fminf(mn2, h2);
            s3 += h3; q3 = fmaf(h3, h3, q3); mx3 = fmaxf(mx3, h3); mn3 = fminf(mn3, h3);
        }
        size_t R = (size_t)(b * NPTS + r) * O + o;
        *(float4*)&HMAX[R] = make_float4(mx0, mx1, mx2, mx3);
        *(float4*)&HMIN[R] = make_float4(mn0, mn1, mn2, mn3);
    }
    float* my = &sh[threadIdx.x * 8];
    my[0] = s0; my[1] = s1; my[2] = s2; my[3] = s3;
    my[4] = q0; my[5] = q1; my[6] = q2; my[7] = q3;
    __syncthreads();
    if (threadIdx.x < TPR) {
        float a[8];
#pragma unroll
        for (int c = 0; c < 8; ++c) a[c] = sh[threadIdx.x * 8 + c];
        for (int g = 1; g < RPAR; ++g) {
            const float* p = &sh[(g * TPR + threadIdx.x) * 8];
#pragma unroll
            for (int c = 0; c < 8; ++c) a[c] += p[c];
        }
        float* dst = &PART[((size_t)b * SB + blockIdx.x) * (2 * O)];
#pragma unroll
        for (int c = 0; c < 4; ++c) { dst[o + c] = a[c]; dst[O + o + c] = a[4 + c]; }
    }
}

// ---------------------------------------------------------------- PART -> PART2
template<int O>
__global__ __launch_bounds__(256) void part_reduce_kernel(const float* __restrict__ PART,
                                                          float* __restrict__ PART2) {
    constexpr int ROWS = BATCH * SB;
    constexpr int RPG = ROWS / PR;
    int g = blockIdx.x;
    for (int col = threadIdx.x; col < 2 * O; col += 256) {
        float s = 0.f;
        for (int r = 0; r < RPG; ++r)
            s += PART[(size_t)(g * RPG + r) * (2 * O) + col];
        PART2[(size_t)g * (2 * O) + col] = s;
    }
}

template<int O>
__global__ void bnp_kernel(const float* __restrict__ PART2, const float* __restrict__ g,
                           const float* __restrict__ beta, float* __restrict__ bnp) {
    int o = threadIdx.x;
    float s = 0.f, ss = 0.f;
    for (int p = 0; p < PR; ++p) {
        s += PART2[(size_t)p * (2 * O) + o];
        ss += PART2[(size_t)p * (2 * O) + O + o];
    }
    const float cnt = (float)NROWS * (float)KNN;
    float m = s / cnt;
    float var = ss / cnt - m * m;
    float sc = g[o] / sqrtf(var + EPSV);
    bnp[o] = sc;
    bnp[O + o] = beta[o] - m * sc;
}

// ---------------------------------------------------------------- apply (stages 1..3)
template<int O>
__global__ __launch_bounds__(256) void applyb_kernel(const float* __restrict__ HMAX,
                                                     const float* __restrict__ HMIN,
                                                     const float* __restrict__ bnp,
                                                     float* __restrict__ Xn) {
    constexpr int TPR = O / 4;
    int e = blockIdx.x * 256 + threadIdx.x;
    int o = (e % TPR) * 4;
    size_t R = (size_t)(e / TPR) * O + o;
    const float4 hx = *(const float4*)&HMAX[R];
    const float4 hn = *(const float4*)&HMIN[R];
    float4 out;
    { float sc = bnp[o + 0], t = bnp[O + o + 0]; out.x = fmaxf(fmaf(sc, (sc >= 0.f) ? hx.x : hn.x, t), 0.f); }
    { float sc = bnp[o + 1], t = bnp[O + o + 1]; out.y = fmaxf(fmaf(sc, (sc >= 0.f) ? hx.y : hn.y, t), 0.f); }
    { float sc = bnp[o + 2], t = bnp[O + o + 2]; out.z = fmaxf(fmaf(sc, (sc >= 0.f) ? hx.z : hn.z, t), 0.f); }
    { float sc = bnp[o + 3], t = bnp[O + o + 3]; out.w = fmaxf(fmaf(sc, (sc >= 0.f) ? hx.w : hn.w, t), 0.f); }
    *(float4*)&Xn[R] = out;
}

// ---------------------------------------------------------------- stage-4 apply: dense -> point-max -> G0T
__global__ __launch_bounds__(256) void applyb4_kernel(const float* __restrict__ HMAX,
                                                      const float* __restrict__ HMIN,
                                                      const float* __restrict__ bnp,
                                                      float* __restrict__ g0T) {
    constexpr int O = 256;
    constexpr int TPR = O / 4;
    constexpr int RPAR = 256 / TPR;
    constexpr int AB = 32;
    constexpr int RPB = NPTS / AB;
    __shared__ float sh[256 * 4];
    int b = blockIdx.z;
    int otid = threadIdx.x & (TPR - 1);
    int o = otid * 4;
    int rsub = threadIdx.x >> 6;
    int rbase = blockIdx.x * RPB;
    float sc0 = bnp[o + 0], t0 = bnp[O + o + 0];
    float sc1 = bnp[o + 1], t1 = bnp[O + o + 1];
    float sc2 = bnp[o + 2], t2 = bnp[O + o + 2];
    float sc3 = bnp[o + 3], t3 = bnp[O + o + 3];
    float ym0 = 0.f, ym1 = 0.f, ym2 = 0.f, ym3 = 0.f;
    for (int r = rbase + rsub; r < rbase + RPB; r += RPAR) {
        size_t R = (size_t)(b * NPTS + r) * O + o;
        const float4 hx = *(const float4*)&HMAX[R];
        const float4 hn = *(const float4*)&HMIN[R];
        ym0 = fmaxf(ym0, fmaf(sc0, (sc0 >= 0.f) ? hx.x : hn.x, t0));
        ym1 = fmaxf(ym1, fmaf(sc1, (sc1 >= 0.f) ? hx.y : hn.y, t1));
        ym2 = fmaxf(ym2, fmaf(sc2, (sc2 >= 0.f) ? hx.z : hn.z, t2));
        ym3 = fmaxf(ym3, fmaf(sc3, (sc3 >= 0.f) ? hx.w : hn.w, t3));
    }
    float* my = &sh[threadIdx.x * 4];
    my[0] = ym0; my[1] = ym1; my[2] = ym2; my[3] = ym3;
    __syncthreads();
    if (threadIdx.x < TPR) {
        float a0 = ym0, a1 = ym1, a2 = ym2, a3 = ym3;
        for (int g = 1; g < RPAR; ++g) {
            const float* p = &sh[(g * TPR + threadIdx.x) * 4];
            a0 = fmaxf(a0, p[0]); a1 = fmaxf(a1, p[1]);
            a2 = fmaxf(a2, p[2]); a3 = fmaxf(a3, p[3]);
        }
        a0 = fmaxf(a0, 0.f); a1 = fmaxf(a1, 0.f);
        a2 = fmaxf(a2, 0.f); a3 = fmaxf(a3, 0.f);
        atomicMax((int*)&g0T[(o + 0) * 8 + b], __float_as_int(a0));
        atomicMax((int*)&g0T[(o + 1) * 8 + b], __float_as_int(a1));
        atomicMax((int*)&g0T[(o + 2) * 8 + b], __float_as_int(a2));
        atomicMax((int*)&g0T[(o + 3) * 8 + b], __float_as_int(a3));
    }
}

// ---------------------------------------------------------------- point-max of X2/X3 into G0T channels [256,448)
__global__ __launch_bounds__(256) void gmax23_kernel(const float* __restrict__ X2,
                                                     const float* __restrict__ X3,
                                                     float* __restrict__ g0T) {
    int b = blockIdx.x;
    int n0 = blockIdx.y * 32;
    int o = threadIdx.x;
    if (o >= 192) return;
    const float* src; int col, stride, ch;
    if (o < 128) { src = X3; col = o;       stride = 128; ch = 256 + o; }
    else         { src = X2; col = o - 128; stride = 64;  ch = 384 + (o - 128); }
    float m = 0.f;
#pragma unroll 8
    for (int n = n0; n < n0 + 32; ++n)
        m = fmaxf(m, src[((size_t)(b * NPTS + n)) * stride + col]);
    atomicMax((int*)&g0T[ch * 8 + b], __float_as_int(m));
}

// ---------------------------------------------------------------- fc weight transpose
__global__ __launch_bounds__(256) void transpose_kernel(const float* __restrict__ w,
                                                        float* __restrict__ wT, int O, int Cc) {
    int e = blockIdx.x * 256 + threadIdx.x;
    if (e >= O * Cc) return;
    int o = e / Cc, c = e - o * Cc;
    wT[c * O + o] = w[e];
}

// ---------------------------------------------------------------- fc1 + bnf1 + relu
__global__ __launch_bounds__(64) void fc1_kernel(const float* __restrict__ g0T,
                                                 const float* __restrict__ w1T,
                                                 const float* __restrict__ b1,
                                                 const float* __restrict__ bng,
                                                 const float* __restrict__ bnb,
                                                 float* __restrict__ A) {
    int o = blockIdx.x * 64 + threadIdx.x;
    float acc[8] = {};
    for (int c = 0; c < 448; ++c) {
        float wv = w1T[c * 256 + o];
        const float4 h0 = *(const float4*)&g0T[c * 8];
        const float4 h1 = *(const float4*)&g0T[c * 8 + 4];
        acc[0] = fmaf(wv, h0.x, acc[0]); acc[1] = fmaf(wv, h0.y, acc[1]);
        acc[2] = fmaf(wv, h0.z, acc[2]); acc[3] = fmaf(wv, h0.w, acc[3]);
        acc[4] = fmaf(wv, h1.x, acc[4]); acc[5] = fmaf(wv, h1.y, acc[5]);
        acc[6] = fmaf(wv, h1.z, acc[6]); acc[7] = fmaf(wv, h1.w, acc[7]);
    }
    float bb = b1[o];
    float h[8], m = 0.f;
#pragma unroll
    for (int b = 0; b < 8; ++b) { h[b] = acc[b] + bb; m += h[b]; }
    m *= 0.125f;
    float var = 0.f;
#pragma unroll
    for (int b = 0; b < 8; ++b) { float d = h[b] - m; var = fmaf(d, d, var); }
    var *= 0.125f;
    float sc = bng[o] / sqrtf(var + EPSV);
    float t = bnb[o] - m * sc;
#pragma unroll
    for (int b = 0; b < 8; ++b) A[o * 8 + b] = fmaxf(fmaf(sc, h[b], t), 0.f);
}

// ---------------------------------------------------------------- fc2..fc4 tail (one block)
__global__ __launch_bounds__(256) void tail_kernel(const float* __restrict__ A,
                                                   const float* __restrict__ w2T, const float* __restrict__ b2,
                                                   const float* __restrict__ g2, const float* __restrict__ be2,
                                                   const float* __restrict__ w3T, const float* __restrict__ b3,
                                                   const float* __restrict__ g3, const float* __restrict__ be3,
                                                   const float* __restrict__ w4, const float* __restrict__ b4,
                                                   float* __restrict__ out) {
    __shared__ __align__(16) float B2[128 * 8];
    __shared__ __align__(16) float C3[16 * 8];
    int tid = threadIdx.x;
    if (tid < 128) {
        int o = tid;
        float acc[8] = {};
        for (int c = 0; c < 256; ++c) {
            float wv = w2T[c * 128 + o];
            const float4 a0 = *(const float4*)&A[c * 8];
            const float4 a1 = *(const float4*)&A[c * 8 + 4];
            acc[0] = fmaf(wv, a0.x, acc[0]); acc[1] = fmaf(wv, a0.y, acc[1]);
            acc[2] = fmaf(wv, a0.z, acc[2]); acc[3] = fmaf(wv, a0.w, acc[3]);
            acc[4] = fmaf(wv, a1.x, acc[4]); acc[5] = fmaf(wv, a1.y, acc[5]);
            acc[6] = fmaf(wv, a1.z, acc[6]); acc[7] = fmaf(wv, a1.w, acc[7]);
        }
        float bb = b2[o];
        float h[8], m = 0.f;
#pragma unroll
        for (int b = 0; b < 8; ++b) { h[b] = acc[b] + bb; m += h[b]; }
        m *= 0.125f;
        float var = 0.f;
#pragma unroll
        for (int b = 0; b < 8; ++b) { float d = h[b] - m; var = fmaf(d, d, var); }
        var *= 0.125f;
        float sc = g2[o] / sqrtf(var + EPSV);
        float t = be2[o] - m * sc;
#pragma unroll
        for (int b = 0; b < 8; ++b) B2[o * 8 + b] = fmaxf(fmaf(sc, h[b], t), 0.f);
    }
    __syncthreads();
    if (tid < 16) {
        int o = tid;
        float acc[8] = {};
        for (int c = 0; c < 128; ++c) {
            float wv = w3T[c * 16 + o];
            const float4 a0 = *(const float4*)&B2[c * 8];
            const float4 a1 = *(const float4*)&B2[c * 8 + 4];
            acc[0] = fmaf(wv, a0.x, acc[0]); acc[1] = fmaf(wv, a0.y, acc[1]);
            acc[2] = fmaf(wv, a0.z, acc[2]); acc[3] = fmaf(wv, a0.w, acc[3]);
            acc[4] = fmaf(wv, a1.x, acc[4]); acc[5] = fmaf(wv, a1.y, acc[5]);
            acc[6] = fmaf(wv, a1.z, acc[6]); acc[7] = fmaf(wv, a1.w, acc[7]);
        }
        float bb = b3[o];
        float h[8], m = 0.f;
#pragma unroll
        for (int b = 0; b < 8; ++b) { h[b] = acc[b] + bb; m += h[b]; }
        m *= 0.125f;
        float var = 0.f;
#pragma unroll
        for (int b = 0; b < 8; ++b) { float d = h[b] - m; var = fmaf(d, d, var); }
        var *= 0.125f;
        float sc = g3[o] / sqrtf(var + EPSV);
        float t = be3[o] - m * sc;
#pragma unroll
        for (int b = 0; b < 8; ++b) C3[o * 8 + b] = fmaxf(fmaf(sc, h[b], t), 0.f);
    }
    __syncthreads();
    if (tid < 8) {
        int b = tid;
        float acc = b4[0];
#pragma unroll
        for (int c = 0; c < 16; ++c) acc = fmaf(w4[c], C3[c * 8 + b], acc);
        out[b] = acc;
    }
}

// ================================================================ host side
struct Arena {
    char* base; size_t off, cap; bool ok;
    Arena(void* b, size_t c) : base((char*)b), off(0), cap(c), ok(true) {}
    void* get(size_t bytes) {
        char* p = base + off;
        off += (bytes + 255) & ~(size_t)255;
        if (off > cap) ok = false;
        return p;
    }
};

// one EdgeConv stage, output stored to Xout (stages 1..3)
template<int C, int O>
static void run_stage(const float* Xin, float* Xout, const float* W, const float* bias,
                      const float* g, const float* be, float* SCRBIG, float* UVA,
                      u16* XPH, u16* XPL, u16* WPH, u16* WPL,
                      u16* IDX, float* SQ, float* PART, float* PART2, float* BNP, hipStream_t s) {
    dim3 blk(256);
    float* HMAX = SCRBIG;
    float* HMIN = SCRBIG + (size_t)NROWS * O;
    u64* CANDB = (u64*)SCRBIG;                   // alias: dead before statsb writes HMAX/HMIN
    int* CNTS = (int*)(CANDB + (size_t)NROWS * NCH * KC2);
    if constexpr (C >= 32) {
        sqnorm_kernel<C><<<NROWS / 256, blk, 0, s>>>(Xin, SQ);
        split_pack_kernel<C><<<NROWS * C / 8 / 256, blk, 0, s>>>(Xin, XPH, XPL);
        knn_kernel<C><<<dim3(NCH, NPTS / 16, BATCH), blk, 0, s>>>(XPH, XPL, SQ, CANDB, CNTS);
        knn_merge_kernel<<<dim3(NPTS / 4, 1, BATCH), blk, 0, s>>>(CANDB, CNTS, IDX);
        wsplit_pack_kernel<C, O><<<(2 * O * C / 8 + 255) / 256, blk, 0, s>>>(W, WPH, WPL);
        uvb_mfma_kernel<C, O><<<dim3(2 * O / 64, NPTS / 64, BATCH), blk, 0, s>>>(XPH, XPL, WPH, WPL, bias, UVA);
    } else {
        // stage 1: exact f32, fused dist+topk from LDS-resident points
        topk1_kernel<<<dim3(NPTS / 4, 1, BATCH), blk, 0, s>>>(Xin, IDX);
        uvb_gemm_kernel<C, O><<<dim3(2 * O / 64, NPTS / 64, BATCH), blk, 0, s>>>(Xin, W, bias, UVA);
    }
    statsb_kernel<O><<<dim3(SB, 1, BATCH), blk, 0, s>>>(UVA, IDX, PART, HMAX, HMIN);
    part_reduce_kernel<O><<<PR, blk, 0, s>>>(PART, PART2);
    bnp_kernel<O><<<1, O, 0, s>>>(PART2, g, be, BNP);
    applyb_kernel<O><<<NROWS * (O / 4) / 256, blk, 0, s>>>(HMAX, HMIN, BNP, Xout);
}

// stage 4
static void run_stage4(const float* Xin, const float* W, const float* bias,
                       const float* g, const float* be, float* SCRBIG, float* UVA,
                       u16* XPH, u16* XPL, u16* WPH, u16* WPL,
                       u16* IDX, float* SQ, float* PART, float* PART2, float* BNP, float* G0T,
                       hipStream_t s) {
    constexpr int C = 128;
    dim3 blk(256);
    float* HMAX = SCRBIG;
    float* HMIN = SCRBIG + (size_t)NROWS * 256;
    u64* CANDB = (u64*)SCRBIG;
    int* CNTS = (int*)(CANDB + (size_t)NROWS * NCH * KC2);
    sqnorm_kernel<C><<<NROWS / 256, blk, 0, s>>>(Xin, SQ);
    split_pack_kernel<C><<<NROWS * C / 8 / 256, blk, 0, s>>>(Xin, XPH, XPL);
    knn_kernel<C><<<dim3(NCH, NPTS / 16, BATCH), blk, 0, s>>>(XPH, XPL, SQ, CANDB, CNTS);
    knn_merge_kernel<<<dim3(NPTS / 4, 1, BATCH), blk, 0, s>>>(CANDB, CNTS, IDX);
    wsplit_pack_kernel<C, 256><<<(512 * C / 8 + 255) / 256, blk, 0, s>>>(W, WPH, WPL);
    uvb_mfma_kernel<C, 256><<<dim3(8, NPTS / 64, BATCH), blk, 0, s>>>(XPH, XPL, WPH, WPL, bias, UVA);
    statsb_kernel<256><<<dim3(SB, 1, BATCH), blk, 0, s>>>(UVA, IDX, PART, HMAX, HMIN);
    part_reduce_kernel<256><<<PR, blk, 0, s>>>(PART, PART2);
    bnp_kernel<256><<<1, 256, 0, s>>>(PART2, g, be, BNP);
    fill_zero_kernel<<<14, blk, 0, s>>>(G0T, 448 * 8);
    applyb4_kernel<<<dim3(32, 1, BATCH), blk, 0, s>>>(HMAX, HMIN, BNP, G0T);
}

extern "C" void kernel_launch(void* const* d_in, const int* in_sizes, int n_in,
                              void* d_out, int out_size, void* d_ws, size_t ws_size,
                              hipStream_t stream) {
    float* out = (float*)d_out;
    if (n_in < 31) { diag_kernel<<<1, 64, 0, stream>>>(out, 9000.f); return; }

    const float* x       = (const float*)d_in[0];
    const float* cw[4]   = {(const float*)d_in[1], (const float*)d_in[5], (const float*)d_in[9],  (const float*)d_in[13]};
    const float* cb[4]   = {(const float*)d_in[2], (const float*)d_in[6], (const float*)d_in[10], (const float*)d_in[14]};
    const float* bg[4]   = {(const float*)d_in[3], (const float*)d_in[7], (const float*)d_in[11], (const float*)d_in[15]};
    const float* bb[4]   = {(const float*)d_in[4], (const float*)d_in[8], (const float*)d_in[12], (const float*)d_in[16]};
    const float* fc1_w = (const float*)d_in[17]; const float* fc1_b = (const float*)d_in[18];
    const float* bnf1_g = (const float*)d_in[19]; const float* bnf1_b = (const float*)d_in[20];
    const float* fc2_w = (const float*)d_in[21]; const float* fc2_b = (const float*)d_in[22];
    const float* bnf2_g = (const float*)d_in[23]; const float* bnf2_b = (const float*)d_in[24];
    const float* fc3_w = (const float*)d_in[25]; const float* fc3_b = (const float*)d_in[26];
    const float* bnf3_g = (const float*)d_in[27]; const float* bnf3_b = (const float*)d_in[28];
    const float* fc4_w = (const float*)d_in[29]; const float* fc4_b = (const float*)d_in[30];

    Arena ar(d_ws, ws_size);
    float* X1 = (float*)ar.get((size_t)NROWS * 64 * 4);
    float* X2 = (float*)ar.get((size_t)NROWS * 64 * 4);
    float* X3 = (float*)ar.get((size_t)NROWS * 128 * 4);
    u16* IDX = (u16*)ar.get((size_t)NROWS * KNN * 2);
    float* SQ = (float*)ar.get((size_t)NROWS * 4);
    float* PART = (float*)ar.get((size_t)BATCH * SB * 512 * 4);
    float* PART2 = (float*)ar.get((size_t)PR * 512 * 4);
    float* BNP = (float*)ar.get(512 * 4);
    float* G0T = (float*)ar.get(448 * 8 * 4);
    float* ABUF = (float*)ar.get(256 * 8 * 4);
    u16* XPH = (u16*)ar.get((size_t)NROWS * 128 * 2);
    u16* XPL = (u16*)ar.get((size_t)NROWS * 128 * 2);
    u16* WPH = (u16*)ar.get(512 * 128 * 2);
    u16* WPL = (u16*)ar.get(512 * 128 * 2);
    float* SCRBIG = (float*)ar.get((size_t)4 * NPTS * NPTS * 4);  // CAND+CNTS / HMAX+HMIN+UVA / W-transposes
    if (!ar.ok) {
        diag_kernel<<<1, 64, 0, stream>>>(out, 3000.f + (float)(ws_size >> 20));
        return;
    }
    float* UVA = SCRBIG + (size_t)2 * NPTS * NPTS;

    dim3 blk(256);
    run_stage<3, 64>(x, X1, cw[0], cb[0], bg[0], bb[0], SCRBIG, UVA, XPH, XPL, WPH, WPL, IDX, SQ, PART, PART2, BNP, stream);
    run_stage<64, 64>(X1, X2, cw[1], cb[1], bg[1], bb[1], SCRBIG, UVA, XPH, XPL, WPH, WPL, IDX, SQ, PART, PART2, BNP, stream);
    run_stage<64, 128>(X2, X3, cw[2], cb[2], bg[2], bb[2], SCRBIG, UVA, XPH, XPL, WPH, WPL, IDX, SQ, PART, PART2, BNP, stream);
    run_stage4(X3, cw[3], cb[3], bg[3], bb[3], SCRBIG, UVA, XPH, XPL, WPH, WPL, IDX, SQ, PART, PART2, BNP, G0T, stream);

    gmax23_kernel<<<dim3(BATCH, 64), blk, 0, stream>>>(X2, X3, G0T);

    float* W1T = SCRBIG;
    float* W2T = W1T + 448 * 256;
    float* W3T = W2T + 256 * 128;
    transpose_kernel<<<(256 * 448 + 255) / 256, blk, 0, stream>>>(fc1_w, W1T, 256, 448);
    transpose_kernel<<<(128 * 256 + 255) / 256, blk, 0, stream>>>(fc2_w, W2T, 128, 256);
    transpose_kernel<<<(16 * 128 + 255) / 256, blk, 0, stream>>>(fc3_w, W3T, 16, 128);
    fc1_kernel<<<4, 64, 0, stream>>>(G0T, W1T, fc1_b, bnf1_g, bnf1_b, ABUF);
    tail_kernel<<<1, 256, 0, stream>>>(ABUF, W2T, fc2_b, bnf2_g, bnf2_b,
                                       W3T, fc3_b, bnf3_g, bnf3_b, fc4_w, fc4_b, out);
}